// Round 9
// baseline (1990.652 us; speedup 1.0000x reference)
//
#include <hip/hip_runtime.h>
#include <math.h>

#define DEV static __device__ __forceinline__

constexpr int H    = 128;
constexpr int Ksub = 12;
constexpr int S    = 16384;
constexpr int SK   = S * Ksub;      // 196608
constexpr int NTOT = 4096;

typedef __attribute__((ext_vector_type(8))) short bhalf8;   // 8 bf16 (4 VGPRs)
typedef __attribute__((ext_vector_type(4))) float floatx4;  // MFMA accumulator

DEV float4 ld4(const float* p) { return *(const float4*)p; }
DEV void   st4(float* p, float4 v) { *(float4*)p = v; }

DEV ushort f2b(float f) {                       // fp32 -> bf16 RNE
  unsigned x = __float_as_uint(f);
  return (ushort)((x + 0x7FFFu + ((x >> 16) & 1u)) >> 16);
}
DEV float b2f(ushort u) { return __uint_as_float(((unsigned)u) << 16); }

DEV void st_hl(ushort* hi, ushort* lo, float v) {
  ushort h = f2b(v);
  *hi = h;
  *lo = f2b(v - b2f(h));
}
DEV float ld_hl(const ushort* hi, const ushort* lo) {
  return b2f(*hi) + b2f(*lo);
}

DEV void split8(const float* v, bhalf8& hi, bhalf8& lo) {
#pragma unroll
  for (int j = 0; j < 8; ++j) {
    ushort hv = f2b(v[j]);
    hi[j] = (short)hv;
    lo[j] = (short)f2b(v[j] - b2f(hv));
  }
}

// ===========================================================================
// mmD: GEMM with A stored as bf16 hi/lo PLANES -> fragments load straight
// into MFMA (no VALU in load path). Split-bf16 3-MFMA math (fp32-accurate).
// Block 128x128, 4 waves (64x64 each). __syncthreads before epilogue ->
// in-place safe.
// PRO: 0 plain | 2 root gather (row*12) | 3 chain-GINE (recombine+split)
// EPI: 0 planes | 1 relu->planes | 2 planes + column stats | 3 combine->planes
//      | 4 (+ recombine(a1 planes)) -> fp32 Yf | 5 plain -> fp32 Yf
// ===========================================================================
template<int PRO, int EPI>
__global__ __launch_bounds__(256) void mmD(
    const ushort* __restrict__ Xhi, const ushort* __restrict__ Xlo,
    const ushort* __restrict__ Whi, const ushort* __restrict__ Wlo,
    const float* __restrict__ bias,
    ushort* __restrict__ Yhi, ushort* __restrict__ Ylo, float* __restrict__ Yf,
    const ushort* __restrict__ a1hi, const ushort* __restrict__ a1lo,
    const float* __restrict__ bpf, const int* __restrict__ ids,
    const float* __restrict__ a2, const float* __restrict__ a3,
    float* __restrict__ stats, const float* __restrict__ bng,
    const float* __restrict__ bnb,
    const float* __restrict__ stats2, const float* __restrict__ bng2,
    const float* __restrict__ bnb2, const float* __restrict__ eps_p,
    float invR, float invR2, size_t ybstr)
{
  __shared__ float sred[2][8][128];
  const int tid  = threadIdx.x;
  const int lane = tid & 63, wv = tid >> 6;
  const int wr = (wv >> 1) * 64, wc = (wv & 1) * 64;
  const int m = lane & 15, q = lane >> 4;
  const int row0 = blockIdx.x * 128;
  const int yb = blockIdx.y;
  Whi  += (size_t)yb * (H * H);
  Wlo  += (size_t)yb * (H * H);
  bias += yb * H;
  Yhi  += (size_t)yb * ybstr;
  Ylo  += (size_t)yb * ybstr;

  float scal = 1.0f;
  if (PRO == 3) scal = 1.0f + eps_p[0];

  floatx4 acc[4][4];
#pragma unroll
  for (int i = 0; i < 4; ++i)
#pragma unroll
    for (int j = 0; j < 4; ++j) acc[i][j] = (floatx4){0.f, 0.f, 0.f, 0.f};

  size_t arow[4], brow[4];
  int qi[4] = {0, 0, 0, 0};
  const float* bprow[4] = {nullptr, nullptr, nullptr, nullptr};
#pragma unroll
  for (int i = 0; i < 4; ++i) {
    int grow = row0 + wr + 16 * i + m;
    arow[i] = (size_t)(PRO == 2 ? grow * Ksub : grow) * H;
    if (PRO == 3) {
      qi[i] = grow % Ksub;
      if (qi[i]) bprow[i] = bpf + (size_t)ids[(grow / Ksub) * (Ksub - 1) + qi[i] - 1] * H;
    }
  }
#pragma unroll
  for (int j = 0; j < 4; ++j) brow[j] = (size_t)(wc + 16 * j + m) * H;

#pragma unroll
  for (int s = 0; s < 4; ++s) {
    const int ko = s * 32 + q * 8;
    bhalf8 ahi[4], alo[4];
#pragma unroll
    for (int i = 0; i < 4; ++i) {
      if (PRO == 3) {
        bhalf8 xh = *(const bhalf8*)(Xhi + arow[i] + ko);
        bhalf8 xl = *(const bhalf8*)(Xlo + arow[i] + ko);
        float xv[8];
#pragma unroll
        for (int j = 0; j < 8; ++j)
          xv[j] = b2f((ushort)xh[j]) + b2f((ushort)xl[j]);
        if (qi[i]) {
          bhalf8 ph = *(const bhalf8*)(Xhi + arow[i] - H + ko);
          bhalf8 pl = *(const bhalf8*)(Xlo + arow[i] - H + ko);
          float bv[8];
          *(float4*)&bv[0] = ld4(bprow[i] + ko);
          *(float4*)&bv[4] = ld4(bprow[i] + ko + 4);
#pragma unroll
          for (int j = 0; j < 8; ++j) {
            float pv = b2f((ushort)ph[j]) + b2f((ushort)pl[j]);
            xv[j] = fmaf(scal, xv[j], fmaxf(pv + bv[j], 0.f));
          }
        } else {
#pragma unroll
          for (int j = 0; j < 8; ++j) xv[j] *= scal;
        }
        split8(xv, ahi[i], alo[i]);
      } else {
        ahi[i] = *(const bhalf8*)(Xhi + arow[i] + ko);
        alo[i] = *(const bhalf8*)(Xlo + arow[i] + ko);
      }
    }
    bhalf8 bhi[4], blo[4];
#pragma unroll
    for (int j = 0; j < 4; ++j) {
      bhi[j] = *(const bhalf8*)(Whi + brow[j] + ko);
      blo[j] = *(const bhalf8*)(Wlo + brow[j] + ko);
    }
#pragma unroll
    for (int i = 0; i < 4; ++i)
#pragma unroll
      for (int j = 0; j < 4; ++j) {
        acc[i][j] = __builtin_amdgcn_mfma_f32_16x16x32_bf16(ahi[i], bhi[j], acc[i][j], 0, 0, 0);
        acc[i][j] = __builtin_amdgcn_mfma_f32_16x16x32_bf16(ahi[i], blo[j], acc[i][j], 0, 0, 0);
        acc[i][j] = __builtin_amdgcn_mfma_f32_16x16x32_bf16(alo[i], bhi[j], acc[i][j], 0, 0, 0);
      }
  }

  __syncthreads();   // all loads done -> in-place plane writes are safe

  float psum[4], psq[4];
#pragma unroll
  for (int j = 0; j < 4; ++j) { psum[j] = 0.f; psq[j] = 0.f; }

#pragma unroll
  for (int j = 0; j < 4; ++j) {
    const int col = wc + 16 * j + m;
    const float bcol = bias[col];
    float mu = 0.f, rs = 0.f, gg = 0.f, bb = 0.f;
    float mu2 = 0.f, rs2 = 0.f, gg2 = 0.f, bb2 = 0.f;
    if (EPI == 3) {
      mu = stats[col] * invR;
      rs = rsqrtf(stats[128 + col] * invR - mu * mu + 1e-5f);
      gg = bng[col]; bb = bnb[col];
      mu2 = stats2[col] * invR2;
      rs2 = rsqrtf(stats2[128 + col] * invR2 - mu2 * mu2 + 1e-5f);
      gg2 = bng2[col]; bb2 = bnb2[col];
    }
#pragma unroll
    for (int i = 0; i < 4; ++i) {
      const int rowb = row0 + wr + 16 * i + 4 * q;
#pragma unroll
      for (int r = 0; r < 4; ++r) {
        const int gr = rowb + r;
        const size_t off = (size_t)gr * H + col;
        float y = acc[i][j][r] + bcol;
        if (EPI == 1) y = fmaxf(y, 0.f);
        if (EPI == 3) {
          int nid = ids[gr];
          float vf = (nid >= 0) ? 1.f : 0.f;
          bool root = (gr % Ksub) == 0;
          float t2v = b2f(a1hi[off]) + b2f(a1lo[off]);
          float h1 = fmaf((t2v - mu) * rs, gg, bb);
          float addv;
          if (root) {
            float c3v = a2[(size_t)nid * H + col];
            addv = fmaf((c3v - mu2) * rs2, gg2, bb2);
          } else {
            addv = y + a3[(size_t)(gr / Ksub) * H + col];
          }
          y = vf * fmaxf(h1 + addv, 0.f);
        }
        if (EPI == 4) {
          y += b2f(a1hi[off]) + b2f(a1lo[off]);
          Yf[off] = y;
        } else if (EPI == 5) {
          Yf[off] = y;
        } else {
          st_hl(Yhi + off, Ylo + off, y);
        }
        if (EPI == 2) { psum[j] += y; psq[j] += y * y; }
      }
    }
  }

  if (EPI == 2) {
    const int slot = 4 * (wv >> 1) + q;
#pragma unroll
    for (int j = 0; j < 4; ++j) {
      const int col = wc + 16 * j + m;
      sred[0][slot][col] = psum[j];
      sred[1][slot][col] = psq[j];
    }
    __syncthreads();
    if (tid < 128) {
      float s = 0.f, q2 = 0.f;
#pragma unroll
      for (int t = 0; t < 8; ++t) { s += sred[0][t][tid]; q2 += sred[1][t][tid]; }
      atomicAdd(stats + tid, s);
      atomicAdd(stats + 128 + tid, q2);
    }
  }
}

// ===========================================================================
// mmF: small fp32-A GEMM (canonical path, N=4096). Split-bf16 3-MFMA.
// PRO: 0 plain | 1 gine (1+eps)X + a1.  EPI: 1 relu | 2 raw + stats. fp32 out.
// ===========================================================================
template<int PRO, int EPI>
__global__ __launch_bounds__(256) void mmF(
    const float* __restrict__ X, const ushort* __restrict__ Whi,
    const ushort* __restrict__ Wlo, const float* __restrict__ bias,
    float* __restrict__ Y, const float* __restrict__ a1,
    float* __restrict__ stats, const float* __restrict__ eps_p)
{
  __shared__ float sred[2][8][128];
  const int tid  = threadIdx.x;
  const int lane = tid & 63, wv = tid >> 6;
  const int wr = (wv >> 1) * 64, wc = (wv & 1) * 64;
  const int m = lane & 15, q = lane >> 4;
  const int row0 = blockIdx.x * 128;

  float scal = 1.0f;
  if (PRO == 1) scal = 1.0f + eps_p[0];

  floatx4 acc[4][4];
#pragma unroll
  for (int i = 0; i < 4; ++i)
#pragma unroll
    for (int j = 0; j < 4; ++j) acc[i][j] = (floatx4){0.f, 0.f, 0.f, 0.f};

  size_t arow[4], brow[4];
#pragma unroll
  for (int i = 0; i < 4; ++i) arow[i] = (size_t)(row0 + wr + 16 * i + m) * H;
#pragma unroll
  for (int j = 0; j < 4; ++j) brow[j] = (size_t)(wc + 16 * j + m) * H;

#pragma unroll
  for (int s = 0; s < 4; ++s) {
    const int ko = s * 32 + q * 8;
    bhalf8 bhi[4], blo[4];
#pragma unroll
    for (int j = 0; j < 4; ++j) {
      bhi[j] = *(const bhalf8*)(Whi + brow[j] + ko);
      blo[j] = *(const bhalf8*)(Wlo + brow[j] + ko);
    }
    bhalf8 ahi[4], alo[4];
#pragma unroll
    for (int i = 0; i < 4; ++i) {
      float xv[8];
      *(float4*)&xv[0] = ld4(X + arow[i] + ko);
      *(float4*)&xv[4] = ld4(X + arow[i] + ko + 4);
      if (PRO == 1) {
        float av[8];
        *(float4*)&av[0] = ld4(a1 + arow[i] + ko);
        *(float4*)&av[4] = ld4(a1 + arow[i] + ko + 4);
#pragma unroll
        for (int j = 0; j < 8; ++j) xv[j] = fmaf(scal, xv[j], av[j]);
      }
      split8(xv, ahi[i], alo[i]);
    }
#pragma unroll
    for (int i = 0; i < 4; ++i)
#pragma unroll
      for (int j = 0; j < 4; ++j) {
        acc[i][j] = __builtin_amdgcn_mfma_f32_16x16x32_bf16(ahi[i], bhi[j], acc[i][j], 0, 0, 0);
        acc[i][j] = __builtin_amdgcn_mfma_f32_16x16x32_bf16(ahi[i], blo[j], acc[i][j], 0, 0, 0);
        acc[i][j] = __builtin_amdgcn_mfma_f32_16x16x32_bf16(alo[i], bhi[j], acc[i][j], 0, 0, 0);
      }
  }

  __syncthreads();

  float psum[4], psq[4];
#pragma unroll
  for (int j = 0; j < 4; ++j) { psum[j] = 0.f; psq[j] = 0.f; }

#pragma unroll
  for (int j = 0; j < 4; ++j) {
    const int col = wc + 16 * j + m;
    const float bcol = bias[col];
#pragma unroll
    for (int i = 0; i < 4; ++i) {
      const int rowb = row0 + wr + 16 * i + 4 * q;
#pragma unroll
      for (int r = 0; r < 4; ++r) {
        float y = acc[i][j][r] + bcol;
        if (EPI == 1) y = fmaxf(y, 0.f);
        Y[(size_t)(rowb + r) * H + col] = y;
        if (EPI == 2) { psum[j] += y; psq[j] += y * y; }
      }
    }
  }
  if (EPI == 2) {
    const int slot = 4 * (wv >> 1) + q;
#pragma unroll
    for (int j = 0; j < 4; ++j) {
      const int col = wc + 16 * j + m;
      sred[0][slot][col] = psum[j];
      sred[1][slot][col] = psq[j];
    }
    __syncthreads();
    if (tid < 128) {
      float s = 0.f, q2 = 0.f;
#pragma unroll
      for (int t = 0; t < 8; ++t) { s += sred[0][t][tid]; q2 += sred[1][t][tid]; }
      atomicAdd(stats + tid, s);
      atomicAdd(stats + 128 + tid, q2);
    }
  }
}

// --------------------------------------------------------------------------- prep / misc
__global__ void k_split(const float* __restrict__ src, ushort* __restrict__ hi,
                        ushort* __restrict__ lo, int n) {
  int i = (blockIdx.x * 256 + threadIdx.x) * 4;
  if (i >= n) return;
  float4 v = ld4(src + i);
  float vv[4] = {v.x, v.y, v.z, v.w};
#pragma unroll
  for (int j = 0; j < 4; ++j) st_hl(hi + i + j, lo + i + j, vv[j]);
}

__global__ void k_init_h(ushort* __restrict__ hhi, ushort* __restrict__ hlo,
                         const int* __restrict__ node_ids, const int* __restrict__ atom_ids,
                         const float* __restrict__ atom_tab, const float* __restrict__ dist_tab,
                         const float* __restrict__ log_probs, const float* __restrict__ logp_W,
                         const float* __restrict__ logp_b)
{
  int idx = blockIdx.x * 256 + threadIdx.x;
  if (idx >= SK * 32) return;
  int r = idx >> 5, c4 = (idx & 31) * 4;
  int nid = node_ids[r];
  float valid = nid >= 0 ? 1.f : 0.f;
  int cl = nid >= 0 ? nid : 0;
  int aid = atom_ids[cl];
  int dd = r % Ksub;                         // chain structure: dist == pos in chain
  float lp = log_probs[r / Ksub];
  float4 at = ld4(atom_tab + aid * H + c4);
  float4 dt = ld4(dist_tab + dd * H + c4);
  float4 w  = ld4(logp_W + c4);
  float4 bbv = ld4(logp_b + c4);
  float o[4];
  o[0] = (at.x + dt.x + fmaxf(fmaf(lp, w.x, bbv.x), 0.f)) * valid;
  o[1] = (at.y + dt.y + fmaxf(fmaf(lp, w.y, bbv.y), 0.f)) * valid;
  o[2] = (at.z + dt.z + fmaxf(fmaf(lp, w.z, bbv.z), 0.f)) * valid;
  o[3] = (at.w + dt.w + fmaxf(fmaf(lp, w.w, bbv.w), 0.f)) * valid;
  size_t off = (size_t)r * H + c4;
#pragma unroll
  for (int j = 0; j < 4; ++j) st_hl(hhi + off + j, hlo + off + j, o[j]);
}

__global__ void k_bond_all(const float* __restrict__ bt, const float* __restrict__ lw,
                           const float* __restrict__ lb, float* __restrict__ bp_all)
{
  int mb = blockIdx.x;          // 0..7: l = mb>>1, which = mb&1 (0->W0, 1->W5)
  int c = threadIdx.x;
  int l = mb >> 1, wsel = (mb & 1) ? 5 : 0;
  const float* W = lw + ((size_t)l * 8 + wsel) * H * H;
  const float* b = lb + ((size_t)l * 8 + wsel) * H;
  for (int j = 0; j < 8; ++j) {
    float s = b[c];
    for (int k = 0; k < H; ++k) s = fmaf(bt[j * H + k], W[c * H + k], s);
    bp_all[(size_t)(mb * 8 + j) * H + c] = s;
  }
}

// c1[n] = mean of the 4 root rows (h planes); also zeroes c2f
__global__ void k_c1(const ushort* __restrict__ hhi, const ushort* __restrict__ hlo,
                     float* __restrict__ c1, float* __restrict__ c2f) {
  int idx = blockIdx.x * 256 + threadIdx.x;
  if (idx >= NTOT * 32) return;
  int n = idx >> 5, c4 = (idx & 31) * 4;
  float o[4] = {0.f, 0.f, 0.f, 0.f};
#pragma unroll
  for (int mi = 0; mi < 4; ++mi) {
    size_t off = ((size_t)(4 * n + mi) * Ksub) * H + c4;
#pragma unroll
    for (int j = 0; j < 4; ++j) o[j] += ld_hl(hhi + off + j, hlo + off + j);
  }
  st4(c1 + (size_t)n * H + c4, make_float4(o[0] * .25f, o[1] * .25f, o[2] * .25f, o[3] * .25f));
  st4(c2f + (size_t)n * H + c4, make_float4(0.f, 0.f, 0.f, 0.f));
}

__global__ void k_agg(const float* __restrict__ x, const int* __restrict__ src,
                      const int* __restrict__ dst, const int* __restrict__ bid,
                      const float* __restrict__ bp, float* __restrict__ out, int E)
{
  int idx = blockIdx.x * 256 + threadIdx.x;
  if (idx >= E * 32) return;
  int e = idx >> 5, c4 = (idx & 31) * 4;
  int sv = src[e], dv = dst[e], bb = bid[e];
  float4 xv = ld4(x + (size_t)sv * H + c4);
  float4 bv = ld4(bp + (size_t)bb * H + c4);
  float* o = out + (size_t)dv * H + c4;
  atomicAdd(o + 0, fmaxf(xv.x + bv.x, 0.f));
  atomicAdd(o + 1, fmaxf(xv.y + bv.y, 0.f));
  atomicAdd(o + 2, fmaxf(xv.z + bv.z, 0.f));
  atomicAdd(o + 3, fmaxf(xv.w + bv.w, 0.f));
}

__global__ void k_pool(const ushort* __restrict__ hhi, const ushort* __restrict__ hlo,
                       ushort* __restrict__ shi, ushort* __restrict__ slo) {
  int idx = blockIdx.x * 256 + threadIdx.x;
  if (idx >= S * 32) return;
  int s = idx >> 5, c4 = (idx & 31) * 4;
  float a[4] = {0.f, 0.f, 0.f, 0.f};
  size_t off = ((size_t)s * Ksub) * H + c4;
#pragma unroll
  for (int j = 0; j < Ksub; ++j) {
#pragma unroll
    for (int k = 0; k < 4; ++k) a[k] += ld_hl(hhi + off + k, hlo + off + k);
    off += H;
  }
  size_t so = (size_t)s * H + c4;
#pragma unroll
  for (int k = 0; k < 4; ++k) st_hl(shi + so + k, slo + so + k, a[k]);
}

__global__ __launch_bounds__(128) void k_attn(const ushort* __restrict__ qkhi,
                                              const ushort* __restrict__ qklo,
                                              ushort* __restrict__ ohi,
                                              ushort* __restrict__ olo)
{
  int n = blockIdx.x;
  int c = threadIdx.x;          // c = head*32 + d
  const size_t SH = (size_t)S * H;
  float q[4], kv[4], vv[4];
#pragma unroll
  for (int mi = 0; mi < 4; ++mi) {
    size_t off = (size_t)(n * 4 + mi) * H + c;
    q[mi]  = ld_hl(qkhi + off, qklo + off);
    kv[mi] = ld_hl(qkhi + SH + off, qklo + SH + off);
    vv[mi] = ld_hl(qkhi + 2 * SH + off, qklo + 2 * SH + off);
  }
  const float scale = 0.17677669529663687f;   // 1/sqrt(32)
  float sc[4][4];
#pragma unroll
  for (int m1 = 0; m1 < 4; ++m1)
#pragma unroll
    for (int m2 = 0; m2 < 4; ++m2) {
      float p = q[m1] * kv[m2];
#pragma unroll
      for (int off = 16; off > 0; off >>= 1) p += __shfl_xor(p, off, 32);
      sc[m1][m2] = p * scale;
    }
#pragma unroll
  for (int m1 = 0; m1 < 4; ++m1) {
    float mx = fmaxf(fmaxf(sc[m1][0], sc[m1][1]), fmaxf(sc[m1][2], sc[m1][3]));
    float e0 = expf(sc[m1][0] - mx), e1 = expf(sc[m1][1] - mx);
    float e2 = expf(sc[m1][2] - mx), e3 = expf(sc[m1][3] - mx);
    float inv = 1.f / (e0 + e1 + e2 + e3);
    float o = (e0 * vv[0] + e1 * vv[1] + e2 * vv[2] + e3 * vv[3]) * inv;
    size_t off = (size_t)(n * 4 + m1) * H + c;
    st_hl(ohi + off, olo + off, o);
  }
}

__global__ void k_mean(const float* __restrict__ ha, float* __restrict__ ne) {
  int idx = blockIdx.x * 256 + threadIdx.x;
  if (idx >= NTOT * 32) return;
  int n = idx >> 5, c4 = (idx & 31) * 4;
  float4 a = ld4(ha + (size_t)(n * 4 + 0) * H + c4);
  float4 b = ld4(ha + (size_t)(n * 4 + 1) * H + c4);
  float4 c = ld4(ha + (size_t)(n * 4 + 2) * H + c4);
  float4 d = ld4(ha + (size_t)(n * 4 + 3) * H + c4);
  st4(ne + (size_t)n * H + c4,
      make_float4((a.x + b.x + c.x + d.x) * .25f, (a.y + b.y + c.y + d.y) * .25f,
                  (a.z + b.z + c.z + d.z) * .25f, (a.w + b.w + c.w + d.w) * .25f));
}

__global__ __launch_bounds__(256) void k_bn_stats(const float* __restrict__ X, int R,
                                                  float* __restrict__ stats) {
  __shared__ float sh[2][256];
  int c = threadIdx.x & 127;
  int rr = threadIdx.x >> 7;
  float s = 0.f, s2 = 0.f;
  for (int r = blockIdx.x * 2 + rr; r < R; r += gridDim.x * 2) {
    float v = X[(size_t)r * H + c];
    s += v; s2 += v * v;
  }
  sh[0][threadIdx.x] = s; sh[1][threadIdx.x] = s2;
  __syncthreads();
  if (rr == 0) {
    atomicAdd(&stats[c],       s  + sh[0][threadIdx.x + 128]);
    atomicAdd(&stats[128 + c], s2 + sh[1][threadIdx.x + 128]);
  }
}

__global__ __launch_bounds__(128) void k_finalsum(const float* __restrict__ ne,
                                                  const float* __restrict__ stats,
                                                  const float* __restrict__ g,
                                                  const float* __restrict__ b,
                                                  float* __restrict__ out)
{
  int bg = blockIdx.x;           // graph id 0..63
  int c = threadIdx.x;
  const float invR = 1.0f / (float)NTOT;
  float mu = stats[c] * invR;
  float rs = rsqrtf(stats[128 + c] * invR - mu * mu + 1e-5f);
  float gg = g[c], bb = b[c];
  float acc = 0.f;
  for (int r = 0; r < 64; ++r) {
    float v = ne[(size_t)(bg * 64 + r) * H + c];
    acc += (v - mu) * rs * gg + bb;
  }
  out[(size_t)bg * H + c] = acc;
}

// ---------------------------------------------------------------------------
extern "C" void kernel_launch(void* const* d_in, const int* in_sizes, int n_in,
                              void* d_out, int out_size, void* d_ws, size_t ws_size,
                              hipStream_t stream)
{
  const int*   atom_ids   = (const int*)d_in[0];
  const int*   node_ids   = (const int*)d_in[1];
  const int*   intra_bid  = (const int*)d_in[3];
  const int*   edge_index = (const int*)d_in[4];
  const int*   canon_bid  = (const int*)d_in[5];
  const float* log_probs  = (const float*)d_in[7];
  const float* atom_tab   = (const float*)d_in[8];
  const float* bond_tab   = (const float*)d_in[9];
  const float* dist_tab   = (const float*)d_in[10];
  const float* logp_W     = (const float*)d_in[11];
  const float* logp_b     = (const float*)d_in[12];
  const float* lw         = (const float*)d_in[13];
  const float* lb         = (const float*)d_in[14];
  const float* bn_g       = (const float*)d_in[15];
  const float* bn_b       = (const float*)d_in[16];
  const float* eps        = (const float*)d_in[17];
  const float* mha_in_W   = (const float*)d_in[18];
  const float* mha_in_b   = (const float*)d_in[19];
  const float* mha_out_W  = (const float*)d_in[20];
  const float* mha_out_b  = (const float*)d_in[21];
  const float* ro_g       = (const float*)d_in[22];
  const float* ro_b       = (const float*)d_in[23];

  const int E2 = in_sizes[4] / 2;    // 32768 canonical edges
  const int* src2 = edge_index, *dst2 = edge_index + E2;

  // ---- workspace layout ----
  const size_t SKH = (size_t)SK * H;
  const size_t SH  = (size_t)S * H;
  char* wsb = (char*)d_ws;
  ushort* hhi    = (ushort*)wsb;    wsb += SKH * 2;                 // h hi plane
  ushort* hlo    = (ushort*)wsb;    wsb += SKH * 2;                 // h lo plane
  ushort* thi    = (ushort*)wsb;    wsb += SKH * 2;                 // t hi plane
  ushort* tlo    = (ushort*)wsb;    wsb += SKH * 2;                 // t lo plane
  float*  rproj  = (float*)wsb;     wsb += SH * 4;
  float*  c1     = (float*)wsb;     wsb += (size_t)NTOT * H * 4;
  float*  c2b    = (float*)wsb;     wsb += (size_t)NTOT * H * 4;
  float*  c3     = (float*)wsb;     wsb += (size_t)NTOT * H * 4;
  float*  c2f    = (float*)wsb;     wsb += (size_t)NTOT * H * 4;
  float*  bp_all = (float*)wsb;     wsb += (size_t)64 * H * 4;
  float*  statsF = (float*)wsb;     wsb += 9 * 256 * 4;
  ushort* lwhi   = (ushort*)wsb;    wsb += (size_t)4 * 8 * H * H * 2;
  ushort* lwlo   = (ushort*)wsb;    wsb += (size_t)4 * 8 * H * H * 2;
  ushort* mihi   = (ushort*)wsb;    wsb += (size_t)3 * H * H * 2;
  ushort* milo   = (ushort*)wsb;    wsb += (size_t)3 * H * H * 2;
  ushort* mohi   = (ushort*)wsb;    wsb += (size_t)H * H * 2;
  ushort* molo   = (ushort*)wsb;    wsb += (size_t)H * H * 2;
  float*  ao     = (float*)wsb;     wsb += SH * 4;                  // attn-out fp32
  float*  ne     = (float*)wsb;     wsb += (size_t)NTOT * H * 4;
  // post-loop plane aliases inside t planes (t free after last combine)
  ushort* shi  = thi;               ushort* slo  = tlo;             // hsub [S,H]
  ushort* qkhi = thi + SH;          ushort* qklo = tlo + SH;        // qkv [3,S,H]
  ushort* obhi = thi + 4 * SH;      ushort* oblo = tlo + 4 * SH;    // attn o [S,H]
  float* out = (float*)d_out;

  hipMemsetAsync(statsF, 0, 9 * 256 * sizeof(float), stream);
  const int NLW = 4 * 8 * H * H, NMI = 3 * H * H, NMO = H * H;
  k_split<<<(NLW / 4 + 255) / 256, 256, 0, stream>>>(lw, lwhi, lwlo, NLW);
  k_split<<<(NMI / 4 + 255) / 256, 256, 0, stream>>>(mha_in_W, mihi, milo, NMI);
  k_split<<<(NMO / 4 + 255) / 256, 256, 0, stream>>>(mha_out_W, mohi, molo, NMO);
  k_bond_all<<<8, 128, 0, stream>>>(bond_tab, lw, lb, bp_all);
  k_init_h<<<(SK * 32 + 255) / 256, 256, 0, stream>>>(hhi, hlo, node_ids, atom_ids,
      atom_tab, dist_tab, log_probs, logp_W, logp_b);

  for (int l = 0; l < 4; ++l) {
    const ushort* Whi = lwhi + (size_t)l * 8 * H * H;
    const ushort* Wlo = lwlo + (size_t)l * 8 * H * H;
    const float* bb = lb + (size_t)l * 8 * H;
    const float* g0 = bn_g + (l * 2 + 0) * H, *b0  = bn_b + (l * 2 + 0) * H;
    const float* g1 = bn_g + (l * 2 + 1) * H, *b1v = bn_b + (l * 2 + 1) * H;
    const float* eps0 = eps + l * 2, *eps1 = eps + l * 2 + 1;
    float* st0 = statsF + (size_t)l * 512;
    float* st1 = statsF + (size_t)l * 512 + 256;
    const float* bp0 = bp_all + (size_t)(l * 2 + 0) * 8 * H;
    const float* bp1 = bp_all + (size_t)(l * 2 + 1) * 8 * H;

    // G1: t1 = relu(chain-GINE(h) @ W1^T + b1) -> t planes
    mmD<3, 1><<<SK / 128, 256, 0, stream>>>(hhi, hlo, Whi + 1 * H * H, Wlo + 1 * H * H,
        bb + 1 * H, thi, tlo, nullptr, nullptr, nullptr, bp0, intra_bid,
        nullptr, nullptr, nullptr, nullptr, nullptr, nullptr, nullptr, nullptr,
        eps0, 0.f, 0.f, 0);
    // G2: t2 = t1 @ W2^T + b2 (in place, planes) + BN0 stats
    mmD<0, 2><<<SK / 128, 256, 0, stream>>>(thi, tlo, Whi + 2 * H * H, Wlo + 2 * H * H,
        bb + 2 * H, thi, tlo, nullptr, nullptr, nullptr, nullptr, nullptr,
        nullptr, nullptr, st0, nullptr, nullptr, nullptr, nullptr, nullptr,
        nullptr, 0.f, 0.f, 0);
    // rproj[s] = h[root(s)] @ W4^T + b4 -> fp32
    mmD<2, 5><<<S / 128, 256, 0, stream>>>(hhi, hlo, Whi + 4 * H * H, Wlo + 4 * H * H,
        bb + 4 * H, nullptr, nullptr, rproj, nullptr, nullptr, nullptr, nullptr,
        nullptr, nullptr, nullptr, nullptr, nullptr, nullptr, nullptr, nullptr,
        nullptr, 0.f, 0.f, 0);
    // canonical path (fp32, small)
    k_c1<<<(NTOT * 32 + 255) / 256, 256, 0, stream>>>(hhi, hlo, c1, c2f);
    k_agg<<<(E2 * 32 + 255) / 256, 256, 0, stream>>>(c1, src2, dst2, canon_bid, bp1, c2f, E2);
    mmF<1, 1><<<NTOT / 128, 256, 0, stream>>>(c1, Whi + 6 * H * H, Wlo + 6 * H * H,
        bb + 6 * H, c2b, c2f, nullptr, eps1);
    mmF<0, 2><<<NTOT / 128, 256, 0, stream>>>(c2b, Whi + 7 * H * H, Wlo + 7 * H * H,
        bb + 7 * H, c3, nullptr, st1, nullptr);
    // combine: h = relu( BN0(t2) + (root ? BN1(c3raw[nid]) : h@W3+b3 + rproj[s]) ) * valid
    mmD<0, 3><<<SK / 128, 256, 0, stream>>>(hhi, hlo, Whi + 3 * H * H, Wlo + 3 * H * H,
        bb + 3 * H, hhi, hlo, nullptr, thi, tlo, nullptr, node_ids, c3, rproj,
        st0, g0, b0, st1, g1, b1v, nullptr, 1.0f / (float)SK, 1.0f / (float)NTOT, 0);
  }

  // ---- pooling + MHA + readout ----
  k_pool<<<(S * 32 + 255) / 256, 256, 0, stream>>>(hhi, hlo, shi, slo);
  mmD<0, 0><<<dim3(S / 128, 3), 256, 0, stream>>>(shi, slo, mihi, milo, mha_in_b,
      qkhi, qklo, nullptr, nullptr, nullptr, nullptr, nullptr, nullptr, nullptr,
      nullptr, nullptr, nullptr, nullptr, nullptr, nullptr, nullptr, 0.f, 0.f, SH);
  k_attn<<<NTOT, 128, 0, stream>>>(qkhi, qklo, obhi, oblo);
  mmD<0, 4><<<S / 128, 256, 0, stream>>>(obhi, oblo, mohi, molo, mha_out_b,
      nullptr, nullptr, ao, shi, slo, nullptr, nullptr, nullptr, nullptr,
      nullptr, nullptr, nullptr, nullptr, nullptr, nullptr, nullptr, 0.f, 0.f, 0);
  k_mean<<<(NTOT * 32 + 255) / 256, 256, 0, stream>>>(ao, ne);
  float* stF = statsF + (size_t)8 * 256;
  k_bn_stats<<<512, 256, 0, stream>>>(ne, NTOT, stF);
  k_finalsum<<<64, 128, 0, stream>>>(ne, stF, ro_g, ro_b, out);
}

// Round 10
// 1872.417 us; speedup vs baseline: 1.0631x; 1.0631x over previous
//
#include <hip/hip_runtime.h>
#include <math.h>

#define DEV static __device__ __forceinline__

constexpr int H    = 128;
constexpr int Ksub = 12;
constexpr int S    = 16384;
constexpr int SK   = S * Ksub;      // 196608
constexpr int NTOT = 4096;

typedef __attribute__((ext_vector_type(8))) short bhalf8;   // 8 bf16 (4 VGPRs)
typedef __attribute__((ext_vector_type(4))) float floatx4;  // MFMA accumulator

DEV float4 ld4(const float* p) { return *(const float4*)p; }
DEV void   st4(float* p, float4 v) { *(float4*)p = v; }

DEV ushort f2b(float f) {                       // fp32 -> bf16 RNE
  unsigned x = __float_as_uint(f);
  return (ushort)((x + 0x7FFFu + ((x >> 16) & 1u)) >> 16);
}
DEV float b2f(ushort u) { return __uint_as_float(((unsigned)u) << 16); }

DEV void split8(const float* v, bhalf8& hi, bhalf8& lo) {
#pragma unroll
  for (int j = 0; j < 8; ++j) {
    ushort hv = f2b(v[j]);
    hi[j] = (short)hv;
    lo[j] = (short)f2b(v[j] - b2f(hv));
  }
}

// ===========================================================================
// mm12: fused intra-GINE MLP (SK rows):
//   t1 = relu( ((1+eps)h[r] + (r%12 ? relu(h[r-1]+bp[bid]) : 0)) @ W1^T + b1 )
//   t2 = t1 @ W2^T + b2   (-> Y, + column stats)
// t1 lives only in LDS (packed bf16 hi|lo uint). Block 128x128, 4 waves
// (64x64 each). R7-measured config (<=137us).
// ===========================================================================
__global__ __launch_bounds__(256) void mm12(
    const float* __restrict__ X,
    const ushort* __restrict__ W1hi, const ushort* __restrict__ W1lo,
    const float* __restrict__ b1,
    const ushort* __restrict__ W2hi, const ushort* __restrict__ W2lo,
    const float* __restrict__ b2, float* __restrict__ Y,
    const float* __restrict__ bp, const int* __restrict__ bid,
    const float* __restrict__ eps_p, float* __restrict__ stats)
{
  __shared__ unsigned int tls[128][132];        // 67.6 KB; reused for stats red.
  const int tid  = threadIdx.x;
  const int lane = tid & 63, wv = tid >> 6;
  const int wr = (wv >> 1) * 64, wc = (wv & 1) * 64;
  const int m = lane & 15, q = lane >> 4;
  const int row0 = blockIdx.x * 128;
  const float scal = 1.0f + eps_p[0];

  floatx4 acc[4][4];
#pragma unroll
  for (int i = 0; i < 4; ++i)
#pragma unroll
    for (int j = 0; j < 4; ++j) acc[i][j] = (floatx4){0.f, 0.f, 0.f, 0.f};

  size_t arow[4], brow[4];
  int qi[4];
  const float* bprow[4];
#pragma unroll
  for (int i = 0; i < 4; ++i) {
    int grow = row0 + wr + 16 * i + m;
    arow[i] = (size_t)grow * H;
    qi[i] = grow % Ksub;
    bprow[i] = qi[i] ? (bp + (size_t)bid[(grow / Ksub) * (Ksub - 1) + qi[i] - 1] * H)
                     : nullptr;
  }
#pragma unroll
  for (int j = 0; j < 4; ++j) brow[j] = (size_t)(wc + 16 * j + m) * H;

  // ---- phase 1: t1 = relu(chain(h) @ W1^T + b1) -> LDS ----
#pragma unroll
  for (int s = 0; s < 4; ++s) {
    const int ko = s * 32 + q * 8;
    bhalf8 bhi[4], blo[4];
#pragma unroll
    for (int j = 0; j < 4; ++j) {
      bhi[j] = *(const bhalf8*)(W1hi + brow[j] + ko);
      blo[j] = *(const bhalf8*)(W1lo + brow[j] + ko);
    }
    bhalf8 ahi[4], alo[4];
#pragma unroll
    for (int i = 0; i < 4; ++i) {
      float xv[8];
      *(float4*)&xv[0] = ld4(X + arow[i] + ko);
      *(float4*)&xv[4] = ld4(X + arow[i] + ko + 4);
      if (qi[i]) {
        float pv[8], bv[8];
        *(float4*)&pv[0] = ld4(X + arow[i] - H + ko);
        *(float4*)&pv[4] = ld4(X + arow[i] - H + ko + 4);
        *(float4*)&bv[0] = ld4(bprow[i] + ko);
        *(float4*)&bv[4] = ld4(bprow[i] + ko + 4);
#pragma unroll
        for (int j = 0; j < 8; ++j)
          xv[j] = fmaf(scal, xv[j], fmaxf(pv[j] + bv[j], 0.f));
      } else {
#pragma unroll
        for (int j = 0; j < 8; ++j) xv[j] *= scal;
      }
      split8(xv, ahi[i], alo[i]);
    }
#pragma unroll
    for (int i = 0; i < 4; ++i)
#pragma unroll
      for (int j = 0; j < 4; ++j) {
        acc[i][j] = __builtin_amdgcn_mfma_f32_16x16x32_bf16(ahi[i], bhi[j], acc[i][j], 0, 0, 0);
        acc[i][j] = __builtin_amdgcn_mfma_f32_16x16x32_bf16(ahi[i], blo[j], acc[i][j], 0, 0, 0);
        acc[i][j] = __builtin_amdgcn_mfma_f32_16x16x32_bf16(alo[i], bhi[j], acc[i][j], 0, 0, 0);
      }
  }

  // write t1 (relu) into LDS as packed hi|lo
#pragma unroll
  for (int j = 0; j < 4; ++j) {
    const int col = wc + 16 * j + m;
    const float bcol = b1[col];
#pragma unroll
    for (int i = 0; i < 4; ++i) {
      const int lr = wr + 16 * i + 4 * q;
#pragma unroll
      for (int r = 0; r < 4; ++r) {
        float y = fmaxf(acc[i][j][r] + bcol, 0.f);
        ushort hv = f2b(y);
        ushort lv = f2b(y - b2f(hv));
        tls[lr + r][col] = ((unsigned)hv << 16) | lv;
      }
    }
  }
  __syncthreads();

  // ---- phase 2: t2 = t1 @ W2^T + b2 ----
#pragma unroll
  for (int i = 0; i < 4; ++i)
#pragma unroll
    for (int j = 0; j < 4; ++j) acc[i][j] = (floatx4){0.f, 0.f, 0.f, 0.f};

#pragma unroll
  for (int s = 0; s < 4; ++s) {
    const int ko = s * 32 + q * 8;
    bhalf8 bhi[4], blo[4];
#pragma unroll
    for (int j = 0; j < 4; ++j) {
      bhi[j] = *(const bhalf8*)(W2hi + brow[j] + ko);
      blo[j] = *(const bhalf8*)(W2lo + brow[j] + ko);
    }
    bhalf8 ahi[4], alo[4];
#pragma unroll
    for (int i = 0; i < 4; ++i) {
      const int lr = wr + 16 * i + m;
      uint4 u0 = *(const uint4*)&tls[lr][ko];
      uint4 u1 = *(const uint4*)&tls[lr][ko + 4];
      unsigned uu[8] = {u0.x, u0.y, u0.z, u0.w, u1.x, u1.y, u1.z, u1.w};
#pragma unroll
      for (int j = 0; j < 8; ++j) {
        ahi[i][j] = (short)(uu[j] >> 16);
        alo[i][j] = (short)(uu[j] & 0xffffu);
      }
    }
#pragma unroll
    for (int i = 0; i < 4; ++i)
#pragma unroll
      for (int j = 0; j < 4; ++j) {
        acc[i][j] = __builtin_amdgcn_mfma_f32_16x16x32_bf16(ahi[i], bhi[j], acc[i][j], 0, 0, 0);
        acc[i][j] = __builtin_amdgcn_mfma_f32_16x16x32_bf16(ahi[i], blo[j], acc[i][j], 0, 0, 0);
        acc[i][j] = __builtin_amdgcn_mfma_f32_16x16x32_bf16(alo[i], bhi[j], acc[i][j], 0, 0, 0);
      }
  }
  __syncthreads();   // done reading tls; safe to reuse as stats scratch

  float* sredS = (float*)&tls[0][0];           // [8][128]
  float* sredQ = sredS + 1024;                 // [8][128]
  float psum[4], psq[4];
#pragma unroll
  for (int j = 0; j < 4; ++j) { psum[j] = 0.f; psq[j] = 0.f; }

#pragma unroll
  for (int j = 0; j < 4; ++j) {
    const int col = wc + 16 * j + m;
    const float bcol = b2[col];
#pragma unroll
    for (int i = 0; i < 4; ++i) {
      const int gr = row0 + wr + 16 * i + 4 * q;
#pragma unroll
      for (int r = 0; r < 4; ++r) {
        float y = acc[i][j][r] + bcol;
        Y[(size_t)(gr + r) * H + col] = y;
        psum[j] += y; psq[j] += y * y;
      }
    }
  }
  const int slot = 4 * (wv >> 1) + q;          // col-half waves share slot, cols differ
#pragma unroll
  for (int j = 0; j < 4; ++j) {
    const int col = wc + 16 * j + m;
    sredS[slot * 128 + col] = psum[j];
    sredQ[slot * 128 + col] = psq[j];
  }
  __syncthreads();
  if (tid < 128) {
    float s = 0.f, q2 = 0.f;
#pragma unroll
    for (int t = 0; t < 8; ++t) { s += sredS[t * 128 + tid]; q2 += sredQ[t * 128 + tid]; }
    atomicAdd(stats + tid, s);
    atomicAdd(stats + 128 + tid, q2);
  }
}

// ===========================================================================
// mmB: R4-geometry GEMM (best measured: 2.1 TB/s). Block 128x128, 4 waves
// (64x64 each), straightline K-loop, no dbuf, no LDS operands, no cap.
// PRO: 0 plain | 1 gine (1+eps)X + a1 | 2 root gather (row*12)
// EPI: 0 none | 1 relu | 2 raw write + stats | 3 combine (BN0(a1) +
//      root? BN1(a2[nid]) : y+a3[r/12]; relu*valid) | 4 += a1
// __syncthreads before epilogue -> in-place safe.
// ===========================================================================
template<int PRO, int EPI>
__global__ __launch_bounds__(256) void mmB(
    const float* __restrict__ X, const ushort* __restrict__ Whi,
    const ushort* __restrict__ Wlo, const float* __restrict__ bias,
    float* __restrict__ Y,
    const float* __restrict__ a1, const float* __restrict__ a2,
    const float* __restrict__ a3, const int* __restrict__ ids,
    float* __restrict__ stats, const float* __restrict__ bng,
    const float* __restrict__ bnb,
    const float* __restrict__ stats2, const float* __restrict__ bng2,
    const float* __restrict__ bnb2, const float* __restrict__ eps_p,
    float invR, float invR2, size_t ybstride)
{
  __shared__ float sred[2][8][128];
  const int tid  = threadIdx.x;
  const int lane = tid & 63, wv = tid >> 6;
  const int wr = (wv >> 1) * 64, wc = (wv & 1) * 64;
  const int m = lane & 15, q = lane >> 4;
  const int row0 = blockIdx.x * 128;
  const int yb = blockIdx.y;
  Whi  += (size_t)yb * (H * H);
  Wlo  += (size_t)yb * (H * H);
  bias += yb * H;
  Y    += (size_t)yb * ybstride;

  float scal = 1.0f;
  if (PRO == 1) scal = 1.0f + eps_p[0];

  floatx4 acc[4][4];
#pragma unroll
  for (int i = 0; i < 4; ++i)
#pragma unroll
    for (int j = 0; j < 4; ++j) acc[i][j] = (floatx4){0.f, 0.f, 0.f, 0.f};

  size_t arow[4], brow[4];
#pragma unroll
  for (int i = 0; i < 4; ++i) {
    int grow = row0 + wr + 16 * i + m;
    arow[i] = (size_t)(PRO == 2 ? grow * Ksub : grow) * H;
  }
#pragma unroll
  for (int j = 0; j < 4; ++j) brow[j] = (size_t)(wc + 16 * j + m) * H;

#pragma unroll
  for (int s = 0; s < 4; ++s) {
    const int ko = s * 32 + q * 8;
    bhalf8 bhi[4], blo[4];
#pragma unroll
    for (int j = 0; j < 4; ++j) {
      bhi[j] = *(const bhalf8*)(Whi + brow[j] + ko);
      blo[j] = *(const bhalf8*)(Wlo + brow[j] + ko);
    }
    bhalf8 ahi[4], alo[4];
#pragma unroll
    for (int i = 0; i < 4; ++i) {
      float xv[8];
      *(float4*)&xv[0] = ld4(X + arow[i] + ko);
      *(float4*)&xv[4] = ld4(X + arow[i] + ko + 4);
      if (PRO == 1) {
        float av[8];
        *(float4*)&av[0] = ld4(a1 + arow[i] + ko);
        *(float4*)&av[4] = ld4(a1 + arow[i] + ko + 4);
#pragma unroll
        for (int j = 0; j < 8; ++j) xv[j] = fmaf(scal, xv[j], av[j]);
      }
      split8(xv, ahi[i], alo[i]);
    }
#pragma unroll
    for (int i = 0; i < 4; ++i)
#pragma unroll
      for (int j = 0; j < 4; ++j) {
        acc[i][j] = __builtin_amdgcn_mfma_f32_16x16x32_bf16(ahi[i], bhi[j], acc[i][j], 0, 0, 0);
        acc[i][j] = __builtin_amdgcn_mfma_f32_16x16x32_bf16(ahi[i], blo[j], acc[i][j], 0, 0, 0);
        acc[i][j] = __builtin_amdgcn_mfma_f32_16x16x32_bf16(alo[i], bhi[j], acc[i][j], 0, 0, 0);
      }
  }

  __syncthreads();   // all waves' input loads done -> in-place output safe

  float psum[4], psq[4];
#pragma unroll
  for (int j = 0; j < 4; ++j) { psum[j] = 0.f; psq[j] = 0.f; }

#pragma unroll
  for (int j = 0; j < 4; ++j) {
    const int col = wc + 16 * j + m;
    const float bcol = bias[col];
    float mu = 0.f, rs = 0.f, gg = 0.f, bb = 0.f;
    float mu2 = 0.f, rs2 = 0.f, gg2 = 0.f, bb2 = 0.f;
    if (EPI == 3) {
      mu = stats[col] * invR;
      rs = rsqrtf(stats[128 + col] * invR - mu * mu + 1e-5f);
      gg = bng[col]; bb = bnb[col];
      mu2 = stats2[col] * invR2;
      rs2 = rsqrtf(stats2[128 + col] * invR2 - mu2 * mu2 + 1e-5f);
      gg2 = bng2[col]; bb2 = bnb2[col];
    }
#pragma unroll
    for (int i = 0; i < 4; ++i) {
      const int rowb = row0 + wr + 16 * i + 4 * q;
#pragma unroll
      for (int r = 0; r < 4; ++r) {
        const int gr = rowb + r;
        float y = acc[i][j][r] + bcol;
        if (EPI == 1) y = fmaxf(y, 0.f);
        if (EPI == 4) y += a1[(size_t)gr * H + col];
        if (EPI == 3) {
          int nid = ids[gr];
          float vf = (nid >= 0) ? 1.f : 0.f;
          bool root = (gr % Ksub) == 0;
          float t2v = a1[(size_t)gr * H + col];
          float h1 = fmaf((t2v - mu) * rs, gg, bb);
          float addv;
          if (root) {
            float c3v = a2[(size_t)nid * H + col];
            addv = fmaf((c3v - mu2) * rs2, gg2, bb2);
          } else {
            addv = y + a3[(size_t)(gr / Ksub) * H + col];
          }
          y = vf * fmaxf(h1 + addv, 0.f);
        }
        Y[(size_t)gr * H + col] = y;
        if (EPI == 2) { psum[j] += y; psq[j] += y * y; }
      }
    }
  }

  if (EPI == 2) {
    const int slot = 4 * (wv >> 1) + q;
#pragma unroll
    for (int j = 0; j < 4; ++j) {
      const int col = wc + 16 * j + m;
      sred[0][slot][col] = psum[j];
      sred[1][slot][col] = psq[j];
    }
    __syncthreads();
    if (tid < 128) {
      float s = 0.f, q2 = 0.f;
#pragma unroll
      for (int t = 0; t < 8; ++t) { s += sred[0][t][tid]; q2 += sred[1][t][tid]; }
      atomicAdd(stats + tid, s);
      atomicAdd(stats + 128 + tid, q2);
    }
  }
}

// --------------------------------------------------------------------------- prep / misc
__global__ void k_split(const float* __restrict__ src, ushort* __restrict__ hi,
                        ushort* __restrict__ lo, int n) {
  int i = (blockIdx.x * 256 + threadIdx.x) * 4;
  if (i >= n) return;
  float4 v = ld4(src + i);
  float vv[4] = {v.x, v.y, v.z, v.w};
#pragma unroll
  for (int j = 0; j < 4; ++j) {
    ushort hv = f2b(vv[j]);
    hi[i + j] = hv;
    lo[i + j] = f2b(vv[j] - b2f(hv));
  }
}

__global__ void k_init_h(float* __restrict__ h, const int* __restrict__ node_ids,
                         const int* __restrict__ atom_ids,
                         const float* __restrict__ atom_tab, const float* __restrict__ dist_tab,
                         const float* __restrict__ log_probs, const float* __restrict__ logp_W,
                         const float* __restrict__ logp_b)
{
  int idx = blockIdx.x * 256 + threadIdx.x;
  if (idx >= SK * 32) return;
  int r = idx >> 5, c4 = (idx & 31) * 4;
  int nid = node_ids[r];
  float valid = nid >= 0 ? 1.f : 0.f;
  int cl = nid >= 0 ? nid : 0;
  int aid = atom_ids[cl];
  int dd = r % Ksub;                         // chain structure: dist == pos in chain
  float lp = log_probs[r / Ksub];
  float4 at = ld4(atom_tab + aid * H + c4);
  float4 dt = ld4(dist_tab + dd * H + c4);
  float4 w  = ld4(logp_W + c4);
  float4 bbv = ld4(logp_b + c4);
  float4 o;
  o.x = (at.x + dt.x + fmaxf(fmaf(lp, w.x, bbv.x), 0.f)) * valid;
  o.y = (at.y + dt.y + fmaxf(fmaf(lp, w.y, bbv.y), 0.f)) * valid;
  o.z = (at.z + dt.z + fmaxf(fmaf(lp, w.z, bbv.z), 0.f)) * valid;
  o.w = (at.w + dt.w + fmaxf(fmaf(lp, w.w, bbv.w), 0.f)) * valid;
  st4(h + (size_t)r * H + c4, o);
}

__global__ void k_bond_all(const float* __restrict__ bt, const float* __restrict__ lw,
                           const float* __restrict__ lb, float* __restrict__ bp_all)
{
  int mb = blockIdx.x;          // 0..7: l = mb>>1, which = mb&1 (0->W0, 1->W5)
  int c = threadIdx.x;
  int l = mb >> 1, wsel = (mb & 1) ? 5 : 0;
  const float* W = lw + ((size_t)l * 8 + wsel) * H * H;
  const float* b = lb + ((size_t)l * 8 + wsel) * H;
  for (int j = 0; j < 8; ++j) {
    float s = b[c];
    for (int k = 0; k < H; ++k) s = fmaf(bt[j * H + k], W[c * H + k], s);
    bp_all[(size_t)(mb * 8 + j) * H + c] = s;
  }
}

// c1[n] = mean of the 4 root rows; also zeroes c2f
__global__ void k_c1(const float* __restrict__ h, float* __restrict__ c1,
                     float* __restrict__ c2f) {
  int idx = blockIdx.x * 256 + threadIdx.x;
  if (idx >= NTOT * 32) return;
  int n = idx >> 5, c4 = (idx & 31) * 4;
  float o0 = 0.f, o1 = 0.f, o2 = 0.f, o3 = 0.f;
#pragma unroll
  for (int mi = 0; mi < 4; ++mi) {
    const float* p = h + ((size_t)(4 * n + mi) * Ksub) * H + c4;
    o0 += p[0]; o1 += p[1]; o2 += p[2]; o3 += p[3];
  }
  st4(c1 + (size_t)n * H + c4, make_float4(o0 * .25f, o1 * .25f, o2 * .25f, o3 * .25f));
  st4(c2f + (size_t)n * H + c4, make_float4(0.f, 0.f, 0.f, 0.f));
}

__global__ void k_agg(const float* __restrict__ x, const int* __restrict__ src,
                      const int* __restrict__ dst, const int* __restrict__ bid,
                      const float* __restrict__ bp, float* __restrict__ out, int E)
{
  int idx = blockIdx.x * 256 + threadIdx.x;
  if (idx >= E * 32) return;
  int e = idx >> 5, c4 = (idx & 31) * 4;
  int sv = src[e], dv = dst[e], bb = bid[e];
  float4 xv = ld4(x + (size_t)sv * H + c4);
  float4 bv = ld4(bp + (size_t)bb * H + c4);
  float* o = out + (size_t)dv * H + c4;
  atomicAdd(o + 0, fmaxf(xv.x + bv.x, 0.f));
  atomicAdd(o + 1, fmaxf(xv.y + bv.y, 0.f));
  atomicAdd(o + 2, fmaxf(xv.z + bv.z, 0.f));
  atomicAdd(o + 3, fmaxf(xv.w + bv.w, 0.f));
}

__global__ void k_pool(const float* __restrict__ h, float* __restrict__ hsub) {
  int idx = blockIdx.x * 256 + threadIdx.x;
  if (idx >= S * 32) return;
  int s = idx >> 5, c4 = (idx & 31) * 4;
  float a0 = 0.f, a1 = 0.f, a2 = 0.f, a3 = 0.f;
  const float* p = h + ((size_t)s * Ksub) * H + c4;
#pragma unroll
  for (int j = 0; j < Ksub; ++j) {
    a0 += p[0]; a1 += p[1]; a2 += p[2]; a3 += p[3];
    p += H;
  }
  st4(hsub + (size_t)s * H + c4, make_float4(a0, a1, a2, a3));
}

__global__ __launch_bounds__(128) void k_attn(const float* __restrict__ qb,
                                              const float* __restrict__ kb,
                                              const float* __restrict__ vb,
                                              float* __restrict__ ob)
{
  int n = blockIdx.x;
  int c = threadIdx.x;          // c = head*32 + d
  float q[4], kv[4], vv[4];
#pragma unroll
  for (int mi = 0; mi < 4; ++mi) {
    q[mi]  = qb[(size_t)(n * 4 + mi) * H + c];
    kv[mi] = kb[(size_t)(n * 4 + mi) * H + c];
    vv[mi] = vb[(size_t)(n * 4 + mi) * H + c];
  }
  const float scale = 0.17677669529663687f;   // 1/sqrt(32)
  float sc[4][4];
#pragma unroll
  for (int m1 = 0; m1 < 4; ++m1)
#pragma unroll
    for (int m2 = 0; m2 < 4; ++m2) {
      float p = q[m1] * kv[m2];
#pragma unroll
      for (int off = 16; off > 0; off >>= 1) p += __shfl_xor(p, off, 32);
      sc[m1][m2] = p * scale;
    }
#pragma unroll
  for (int m1 = 0; m1 < 4; ++m1) {
    float mx = fmaxf(fmaxf(sc[m1][0], sc[m1][1]), fmaxf(sc[m1][2], sc[m1][3]));
    float e0 = expf(sc[m1][0] - mx), e1 = expf(sc[m1][1] - mx);
    float e2 = expf(sc[m1][2] - mx), e3 = expf(sc[m1][3] - mx);
    float inv = 1.f / (e0 + e1 + e2 + e3);
    ob[(size_t)(n * 4 + m1) * H + c] =
        (e0 * vv[0] + e1 * vv[1] + e2 * vv[2] + e3 * vv[3]) * inv;
  }
}

__global__ void k_mean(const float* __restrict__ ha, float* __restrict__ ne) {
  int idx = blockIdx.x * 256 + threadIdx.x;
  if (idx >= NTOT * 32) return;
  int n = idx >> 5, c4 = (idx & 31) * 4;
  float4 a = ld4(ha + (size_t)(n * 4 + 0) * H + c4);
  float4 b = ld4(ha + (size_t)(n * 4 + 1) * H + c4);
  float4 c = ld4(ha + (size_t)(n * 4 + 2) * H + c4);
  float4 d = ld4(ha + (size_t)(n * 4 + 3) * H + c4);
  st4(ne + (size_t)n * H + c4,
      make_float4((a.x + b.x + c.x + d.x) * .25f, (a.y + b.y + c.y + d.y) * .25f,
                  (a.z + b.z + c.z + d.z) * .25f, (a.w + b.w + c.w + d.w) * .25f));
}

__global__ __launch_bounds__(256) void k_bn_stats(const float* __restrict__ X, int R,
                                                  float* __restrict__ stats) {
  __shared__ float sh[2][256];
  int c = threadIdx.x & 127;
  int rr = threadIdx.x >> 7;
  float s = 0.f, s2 = 0.f;
  for (int r = blockIdx.x * 2 + rr; r < R; r += gridDim.x * 2) {
    float v = X[(size_t)r * H + c];
    s += v; s2 += v * v;
  }
  sh[0][threadIdx.x] = s; sh[1][threadIdx.x] = s2;
  __syncthreads();
  if (rr == 0) {
    atomicAdd(&stats[c],       s  + sh[0][threadIdx.x + 128]);
    atomicAdd(&stats[128 + c], s2 + sh[1][threadIdx.x + 128]);
  }
}

__global__ __launch_bounds__(128) void k_finalsum(const float* __restrict__ ne,
                                                  const float* __restrict__ stats,
                                                  const float* __restrict__ g,
                                                  const float* __restrict__ b,
                                                  float* __restrict__ out)
{
  int bg = blockIdx.x;           // graph id 0..63
  int c = threadIdx.x;
  const float invR = 1.0f / (float)NTOT;
  float mu = stats[c] * invR;
  float rs = rsqrtf(stats[128 + c] * invR - mu * mu + 1e-5f);
  float gg = g[c], bb = b[c];
  float acc = 0.f;
  for (int r = 0; r < 64; ++r) {
    float v = ne[(size_t)(bg * 64 + r) * H + c];
    acc += (v - mu) * rs * gg + bb;
  }
  out[(size_t)bg * H + c] = acc;
}

// ---------------------------------------------------------------------------
extern "C" void kernel_launch(void* const* d_in, const int* in_sizes, int n_in,
                              void* d_out, int out_size, void* d_ws, size_t ws_size,
                              hipStream_t stream)
{
  const int*   atom_ids   = (const int*)d_in[0];
  const int*   node_ids   = (const int*)d_in[1];
  const int*   intra_bid  = (const int*)d_in[3];
  const int*   edge_index = (const int*)d_in[4];
  const int*   canon_bid  = (const int*)d_in[5];
  const float* log_probs  = (const float*)d_in[7];
  const float* atom_tab   = (const float*)d_in[8];
  const float* bond_tab   = (const float*)d_in[9];
  const float* dist_tab   = (const float*)d_in[10];
  const float* logp_W     = (const float*)d_in[11];
  const float* logp_b     = (const float*)d_in[12];
  const float* lw         = (const float*)d_in[13];
  const float* lb         = (const float*)d_in[14];
  const float* bn_g       = (const float*)d_in[15];
  const float* bn_b       = (const float*)d_in[16];
  const float* eps        = (const float*)d_in[17];
  const float* mha_in_W   = (const float*)d_in[18];
  const float* mha_in_b   = (const float*)d_in[19];
  const float* mha_out_W  = (const float*)d_in[20];
  const float* mha_out_b  = (const float*)d_in[21];
  const float* ro_g       = (const float*)d_in[22];
  const float* ro_b       = (const float*)d_in[23];

  const int E2 = in_sizes[4] / 2;    // 32768 canonical edges
  const int* src2 = edge_index, *dst2 = edge_index + E2;

  // ---- workspace layout ----
  const size_t SKH = (size_t)SK * H;
  const size_t SH  = (size_t)S * H;
  char* wsb = (char*)d_ws;
  float*  h      = (float*)wsb;     wsb += SKH * 4;                 // [SK,H]
  float*  t      = (float*)wsb;     wsb += SKH * 4;                 // [SK,H]
  float*  rproj  = (float*)wsb;     wsb += SH * 4;
  float*  c1     = (float*)wsb;     wsb += (size_t)NTOT * H * 4;
  float*  c2b    = (float*)wsb;     wsb += (size_t)NTOT * H * 4;
  float*  c3     = (float*)wsb;     wsb += (size_t)NTOT * H * 4;
  float*  c2f    = (float*)wsb;     wsb += (size_t)NTOT * H * 4;
  float*  bp_all = (float*)wsb;     wsb += (size_t)64 * H * 4;
  float*  statsF = (float*)wsb;     wsb += 9 * 256 * 4;
  ushort* lwhi   = (ushort*)wsb;    wsb += (size_t)4 * 8 * H * H * 2;
  ushort* lwlo   = (ushort*)wsb;    wsb += (size_t)4 * 8 * H * H * 2;
  ushort* mihi   = (ushort*)wsb;    wsb += (size_t)3 * H * H * 2;
  ushort* milo   = (ushort*)wsb;    wsb += (size_t)3 * H * H * 2;
  ushort* mohi   = (ushort*)wsb;    wsb += (size_t)H * H * 2;
  ushort* molo   = (ushort*)wsb;    wsb += (size_t)H * H * 2;
  // post-loop aliases inside t (t free after last combine)
  float* hsub = t;                           // [S,H]
  float* qkv  = hsub + SH;                   // [3,S,H]
  float* ob   = qkv + 3 * SH;                // [S,H]
  float* ne   = ob + SH;                     // [N,H]
  float* out  = (float*)d_out;

  hipMemsetAsync(statsF, 0, 9 * 256 * sizeof(float), stream);
  const int NLW = 4 * 8 * H * H, NMI = 3 * H * H, NMO = H * H;
  k_split<<<(NLW / 4 + 255) / 256, 256, 0, stream>>>(lw, lwhi, lwlo, NLW);
  k_split<<<(NMI / 4 + 255) / 256, 256, 0, stream>>>(mha_in_W, mihi, milo, NMI);
  k_split<<<(NMO / 4 + 255) / 256, 256, 0, stream>>>(mha_out_W, mohi, molo, NMO);
  k_bond_all<<<8, 128, 0, stream>>>(bond_tab, lw, lb, bp_all);
  k_init_h<<<(SK * 32 + 255) / 256, 256, 0, stream>>>(h, node_ids, atom_ids,
      atom_tab, dist_tab, log_probs, logp_W, logp_b);

  for (int l = 0; l < 4; ++l) {
    const ushort* Whi = lwhi + (size_t)l * 8 * H * H;
    const ushort* Wlo = lwlo + (size_t)l * 8 * H * H;
    const float* bb = lb + (size_t)l * 8 * H;
    const float* g0 = bn_g + (l * 2 + 0) * H, *b0  = bn_b + (l * 2 + 0) * H;
    const float* g1 = bn_g + (l * 2 + 1) * H, *b1v = bn_b + (l * 2 + 1) * H;
    const float* eps0 = eps + l * 2, *eps1 = eps + l * 2 + 1;
    float* st0 = statsF + (size_t)l * 512;
    float* st1 = statsF + (size_t)l * 512 + 256;
    const float* bp0 = bp_all + (size_t)(l * 2 + 0) * 8 * H;
    const float* bp1 = bp_all + (size_t)(l * 2 + 1) * 8 * H;

    // fused: t = (chain-GINE(h) @ W1 -> relu) @ W2 + b2, raw + BN0 stats
    mm12<<<SK / 128, 256, 0, stream>>>(h, Whi + 1 * H * H, Wlo + 1 * H * H, bb + 1 * H,
        Whi + 2 * H * H, Wlo + 2 * H * H, bb + 2 * H, t, bp0, intra_bid, eps0, st0);
    // rproj[s] = h[root(s)] @ W4^T + b4
    mmB<2, 0><<<S / 128, 256, 0, stream>>>(h, Whi + 4 * H * H, Wlo + 4 * H * H,
        bb + 4 * H, rproj, nullptr, nullptr, nullptr, nullptr, nullptr, nullptr,
        nullptr, nullptr, nullptr, nullptr, nullptr, 0.f, 0.f, 0);
    // canonical path
    k_c1<<<(NTOT * 32 + 255) / 256, 256, 0, stream>>>(h, c1, c2f);
    k_agg<<<(E2 * 32 + 255) / 256, 256, 0, stream>>>(c1, src2, dst2, canon_bid, bp1, c2f, E2);
    mmB<1, 1><<<NTOT / 128, 256, 0, stream>>>(c1, Whi + 6 * H * H, Wlo + 6 * H * H,
        bb + 6 * H, c2b, c2f, nullptr, nullptr, nullptr, nullptr, nullptr, nullptr,
        nullptr, nullptr, nullptr, eps1, 0.f, 0.f, 0);
    mmB<0, 2><<<NTOT / 128, 256, 0, stream>>>(c2b, Whi + 7 * H * H, Wlo + 7 * H * H,
        bb + 7 * H, c3, nullptr, nullptr, nullptr, nullptr, st1, nullptr, nullptr,
        nullptr, nullptr, nullptr, nullptr, 0.f, 0.f, 0);
    // combine: h = relu( BN0(t2) + (root ? BN1(c3raw[nid]) : h@W3+b3 + rproj[s]) ) * valid
    mmB<0, 3><<<SK / 128, 256, 0, stream>>>(h, Whi + 3 * H * H, Wlo + 3 * H * H,
        bb + 3 * H, h, t, c3, rproj, node_ids, st0, g0, b0, st1, g1, b1v, nullptr,
        1.0f / (float)SK, 1.0f / (float)NTOT, 0);
  }

  // ---- pooling + MHA + readout ----
  k_pool<<<(S * 32 + 255) / 256, 256, 0, stream>>>(h, hsub);
  mmB<0, 0><<<dim3(S / 128, 3), 256, 0, stream>>>(hsub, mihi, milo, mha_in_b, qkv,
      nullptr, nullptr, nullptr, nullptr, nullptr, nullptr, nullptr, nullptr, nullptr,
      nullptr, nullptr, 0.f, 0.f, SH);
  k_attn<<<NTOT, 128, 0, stream>>>(qkv, qkv + SH, qkv + 2 * SH, ob);
  mmB<0, 4><<<S / 128, 256, 0, stream>>>(ob, mohi, molo, mha_out_b, ob,
      hsub, nullptr, nullptr, nullptr, nullptr, nullptr, nullptr, nullptr, nullptr,
      nullptr, nullptr, 0.f, 0.f, 0);
  k_mean<<<(NTOT * 32 + 255) / 256, 256, 0, stream>>>(ob, ne);
  float* stF = statsF + (size_t)8 * 256;
  k_bn_stats<<<512, 256, 0, stream>>>(ne, NTOT, stF);
  k_finalsum<<<64, 128, 0, stream>>>(ne, stF, ro_g, ro_b, out);
}

// Round 11
// 1576.343 us; speedup vs baseline: 1.2628x; 1.1878x over previous
//
#include <hip/hip_runtime.h>
#include <math.h>

#define DEV static __device__ __forceinline__

constexpr int H    = 128;
constexpr int Ksub = 12;
constexpr int S    = 16384;
constexpr int SK   = S * Ksub;      // 196608
constexpr int NTOT = 4096;

typedef __attribute__((ext_vector_type(8))) short bhalf8;   // 8 bf16 (4 VGPRs)
typedef __attribute__((ext_vector_type(4))) float floatx4;  // MFMA accumulator

DEV float4 ld4(const float* p) { return *(const float4*)p; }
DEV void   st4(float* p, float4 v) { *(float4*)p = v; }

DEV ushort f2b(float f) {                       // fp32 -> bf16 RNE
  unsigned x = __float_as_uint(f);
  return (ushort)((x + 0x7FFFu + ((x >> 16) & 1u)) >> 16);
}
DEV float b2f(ushort u) { return __uint_as_float(((unsigned)u) << 16); }

DEV void split8(const float* v, bhalf8& hi, bhalf8& lo) {
#pragma unroll
  for (int j = 0; j < 8; ++j) {
    ushort hv = f2b(v[j]);
    hi[j] = (short)hv;
    lo[j] = (short)f2b(v[j] - b2f(hv));
  }
}

// stats sites: 8 sharded copies of [sum(128)|sumsq(128)] each (2048 floats/site)

// ===========================================================================
// mm12: fused intra-GINE MLP (SK rows)  [R6 config: 64-row block, lb(256,4)]
//   t1 = relu( ((1+eps)h[r] + (r%12 ? relu(h[r-1]+bp[bid]) : 0)) @ W1^T + b1 )
//   t2 = t1 @ W2^T + b2   -> Y as plain bf16 (element-wise consumer only),
//   staged through LDS for coalesced 16B stores; + sharded column stats.
// ===========================================================================
__global__ __launch_bounds__(256, 4) void mm12(
    const float* __restrict__ X,
    const ushort* __restrict__ W1hi, const ushort* __restrict__ W1lo,
    const float* __restrict__ b1,
    const ushort* __restrict__ W2hi, const ushort* __restrict__ W2lo,
    const float* __restrict__ b2, ushort* __restrict__ Y,
    const float* __restrict__ bp, const int* __restrict__ bid,
    const float* __restrict__ eps_p, float* __restrict__ stats)
{
  __shared__ unsigned int tls[64][132];        // 33.8 KB; reused post-phase2
  const int tid  = threadIdx.x;
  const int lane = tid & 63, wv = tid >> 6;
  const int wr = (wv >> 1) * 32, wc = (wv & 1) * 64;
  const int m = lane & 15, q = lane >> 4;
  const int row0 = blockIdx.x * 64;
  const float scal = 1.0f + eps_p[0];

  floatx4 acc[2][4];
#pragma unroll
  for (int i = 0; i < 2; ++i)
#pragma unroll
    for (int j = 0; j < 4; ++j) acc[i][j] = (floatx4){0.f, 0.f, 0.f, 0.f};

  size_t arow[2], brow[4];
  int qi[2];
  const float* bprow[2];
#pragma unroll
  for (int i = 0; i < 2; ++i) {
    int grow = row0 + wr + 16 * i + m;
    arow[i] = (size_t)grow * H;
    qi[i] = grow % Ksub;
    bprow[i] = qi[i] ? (bp + (size_t)bid[(grow / Ksub) * (Ksub - 1) + qi[i] - 1] * H)
                     : nullptr;
  }
#pragma unroll
  for (int j = 0; j < 4; ++j) brow[j] = (size_t)(wc + 16 * j + m) * H;

  // ---- phase 1: t1 = relu(chain(h) @ W1^T + b1) -> LDS ----
#pragma unroll
  for (int s = 0; s < 4; ++s) {
    const int ko = s * 32 + q * 8;
    bhalf8 bhi[4], blo[4];
#pragma unroll
    for (int j = 0; j < 4; ++j) {
      bhi[j] = *(const bhalf8*)(W1hi + brow[j] + ko);
      blo[j] = *(const bhalf8*)(W1lo + brow[j] + ko);
    }
    bhalf8 ahi[2], alo[2];
#pragma unroll
    for (int i = 0; i < 2; ++i) {
      float xv[8];
      *(float4*)&xv[0] = ld4(X + arow[i] + ko);
      *(float4*)&xv[4] = ld4(X + arow[i] + ko + 4);
      if (qi[i]) {
        float pv[8], bv[8];
        *(float4*)&pv[0] = ld4(X + arow[i] - H + ko);
        *(float4*)&pv[4] = ld4(X + arow[i] - H + ko + 4);
        *(float4*)&bv[0] = ld4(bprow[i] + ko);
        *(float4*)&bv[4] = ld4(bprow[i] + ko + 4);
#pragma unroll
        for (int j = 0; j < 8; ++j)
          xv[j] = fmaf(scal, xv[j], fmaxf(pv[j] + bv[j], 0.f));
      } else {
#pragma unroll
        for (int j = 0; j < 8; ++j) xv[j] *= scal;
      }
      split8(xv, ahi[i], alo[i]);
    }
#pragma unroll
    for (int i = 0; i < 2; ++i)
#pragma unroll
      for (int j = 0; j < 4; ++j) {
        acc[i][j] = __builtin_amdgcn_mfma_f32_16x16x32_bf16(ahi[i], bhi[j], acc[i][j], 0, 0, 0);
        acc[i][j] = __builtin_amdgcn_mfma_f32_16x16x32_bf16(ahi[i], blo[j], acc[i][j], 0, 0, 0);
        acc[i][j] = __builtin_amdgcn_mfma_f32_16x16x32_bf16(alo[i], bhi[j], acc[i][j], 0, 0, 0);
      }
  }

  // write t1 (relu) into LDS as packed hi|lo
#pragma unroll
  for (int j = 0; j < 4; ++j) {
    const int col = wc + 16 * j + m;
    const float bcol = b1[col];
#pragma unroll
    for (int i = 0; i < 2; ++i) {
      const int lr = wr + 16 * i + 4 * q;
#pragma unroll
      for (int r = 0; r < 4; ++r) {
        float y = fmaxf(acc[i][j][r] + bcol, 0.f);
        ushort hv = f2b(y);
        ushort lv = f2b(y - b2f(hv));
        tls[lr + r][col] = ((unsigned)hv << 16) | lv;
      }
    }
  }
  __syncthreads();

  // ---- phase 2: t2 = t1 @ W2^T + b2 ----
#pragma unroll
  for (int i = 0; i < 2; ++i)
#pragma unroll
    for (int j = 0; j < 4; ++j) acc[i][j] = (floatx4){0.f, 0.f, 0.f, 0.f};

#pragma unroll
  for (int s = 0; s < 4; ++s) {
    const int ko = s * 32 + q * 8;
    bhalf8 bhi[4], blo[4];
#pragma unroll
    for (int j = 0; j < 4; ++j) {
      bhi[j] = *(const bhalf8*)(W2hi + brow[j] + ko);
      blo[j] = *(const bhalf8*)(W2lo + brow[j] + ko);
    }
    bhalf8 ahi[2], alo[2];
#pragma unroll
    for (int i = 0; i < 2; ++i) {
      const int lr = wr + 16 * i + m;
      uint4 u0 = *(const uint4*)&tls[lr][ko];
      uint4 u1 = *(const uint4*)&tls[lr][ko + 4];
      unsigned uu[8] = {u0.x, u0.y, u0.z, u0.w, u1.x, u1.y, u1.z, u1.w};
#pragma unroll
      for (int j = 0; j < 8; ++j) {
        ahi[i][j] = (short)(uu[j] >> 16);
        alo[i][j] = (short)(uu[j] & 0xffffu);
      }
    }
#pragma unroll
    for (int i = 0; i < 2; ++i)
#pragma unroll
      for (int j = 0; j < 4; ++j) {
        acc[i][j] = __builtin_amdgcn_mfma_f32_16x16x32_bf16(ahi[i], bhi[j], acc[i][j], 0, 0, 0);
        acc[i][j] = __builtin_amdgcn_mfma_f32_16x16x32_bf16(ahi[i], blo[j], acc[i][j], 0, 0, 0);
        acc[i][j] = __builtin_amdgcn_mfma_f32_16x16x32_bf16(alo[i], bhi[j], acc[i][j], 0, 0, 0);
      }
  }
  __syncthreads();   // done reading tls; reuse: sred (8 KB) + bf16 stage (16 KB)

  float*  sredS = (float*)&tls[0][0];          // [8][128]
  float*  sredQ = sredS + 1024;                // [8][128]
  ushort* stage = (ushort*)(sredQ + 1024);     // [64][128] bf16 of t2

  float psum[4], psq[4];
#pragma unroll
  for (int j = 0; j < 4; ++j) { psum[j] = 0.f; psq[j] = 0.f; }

#pragma unroll
  for (int j = 0; j < 4; ++j) {
    const int col = wc + 16 * j + m;
    const float bcol = b2[col];
#pragma unroll
    for (int i = 0; i < 2; ++i) {
      const int lr = wr + 16 * i + 4 * q;
#pragma unroll
      for (int r = 0; r < 4; ++r) {
        float y = acc[i][j][r] + bcol;
        stage[(lr + r) * 128 + col] = f2b(y);
        psum[j] += y; psq[j] += y * y;
      }
    }
  }
  const int slot = 4 * (wv >> 1) + q;
#pragma unroll
  for (int j = 0; j < 4; ++j) {
    const int col = wc + 16 * j + m;
    sredS[slot * 128 + col] = psum[j];
    sredQ[slot * 128 + col] = psq[j];
  }
  __syncthreads();

  // coalesced bf16 store of the 64x128 tile: 4 iters x 256 thr x 16B
#pragma unroll
  for (int it = 0; it < 4; ++it) {
    int idx = (it * 256 + tid) * 8;            // ushort index; col multiple of 8
    int row = idx >> 7, col = idx & 127;
    *(uint4*)&Y[(size_t)(row0 + row) * H + col] = *(const uint4*)&stage[idx];
  }

  if (tid < 128) {
    float s = 0.f, q2 = 0.f;
#pragma unroll
    for (int t = 0; t < 8; ++t) { s += sredS[t * 128 + tid]; q2 += sredQ[t * 128 + tid]; }
    float* stc = stats + (blockIdx.x & 7) * 256;    // sharded copy
    atomicAdd(stc + tid, s);
    atomicAdd(stc + 128 + tid, q2);
  }
}

// ===========================================================================
// mmN: Y = EPI( PRO(X) @ W^T + bias ).  [R6 config: 64-row, lb(256,4)]
// PRO: 0 plain | 1 gine: (1+eps)*X + a1 (f32) | 2 root gather (row*12)
// EPI: 0 none | 1 relu | 2 raw write + sharded column stats
//      | 3 combine: h1=BN(a1b bf16; stats,g,b);
//            root? h1 + BN(a2[nid];stats2,bng2,bnb2) : h1+y+a3[r/12]; relu*valid
//      | 4 y += a1[r] (f32)
// ===========================================================================
template<int PRO, int EPI>
__global__ __launch_bounds__(256, 4) void mmN(
    const float* __restrict__ X, const ushort* __restrict__ Whi,
    const ushort* __restrict__ Wlo, const float* __restrict__ bias,
    float* __restrict__ Y,
    const float* __restrict__ a1, const ushort* __restrict__ a1b,
    const float* __restrict__ a2, const float* __restrict__ a3,
    const int* __restrict__ ids,
    float* __restrict__ stats, const float* __restrict__ bng,
    const float* __restrict__ bnb,
    const float* __restrict__ stats2, const float* __restrict__ bng2,
    const float* __restrict__ bnb2, const float* __restrict__ eps_p,
    float invR, float invR2, size_t ybstride)
{
  __shared__ float sred[2][8][128];             // stats reduction (EPI==2 only)
  const int tid  = threadIdx.x;
  const int lane = tid & 63, wv = tid >> 6;
  const int wr = (wv >> 1) * 32, wc = (wv & 1) * 64;
  const int m = lane & 15, q = lane >> 4;
  const int row0 = blockIdx.x * 64;
  const int yb = blockIdx.y;
  Whi  += (size_t)yb * (H * H);
  Wlo  += (size_t)yb * (H * H);
  bias += yb * H;
  Y    += (size_t)yb * ybstride;

  float scal = 1.0f;
  if (PRO == 1) scal = 1.0f + eps_p[0];

  floatx4 acc[2][4];
#pragma unroll
  for (int i = 0; i < 2; ++i)
#pragma unroll
    for (int j = 0; j < 4; ++j) acc[i][j] = (floatx4){0.f, 0.f, 0.f, 0.f};

  size_t arow[2], brow[4];
#pragma unroll
  for (int i = 0; i < 2; ++i) {
    int grow = row0 + wr + 16 * i + m;
    arow[i] = (size_t)(PRO == 2 ? grow * Ksub : grow) * H;
  }
#pragma unroll
  for (int j = 0; j < 4; ++j) brow[j] = (size_t)(wc + 16 * j + m) * H;

#pragma unroll
  for (int s = 0; s < 4; ++s) {
    const int ko = s * 32 + q * 8;
    bhalf8 bhi[4], blo[4];
#pragma unroll
    for (int j = 0; j < 4; ++j) {
      bhi[j] = *(const bhalf8*)(Whi + brow[j] + ko);
      blo[j] = *(const bhalf8*)(Wlo + brow[j] + ko);
    }
    bhalf8 ahi[2], alo[2];
#pragma unroll
    for (int i = 0; i < 2; ++i) {
      float xv[8];
      *(float4*)&xv[0] = ld4(X + arow[i] + ko);
      *(float4*)&xv[4] = ld4(X + arow[i] + ko + 4);
      if (PRO == 1) {
        float av[8];
        *(float4*)&av[0] = ld4(a1 + arow[i] + ko);
        *(float4*)&av[4] = ld4(a1 + arow[i] + ko + 4);
#pragma unroll
        for (int j = 0; j < 8; ++j) xv[j] = fmaf(scal, xv[j], av[j]);
      }
      split8(xv, ahi[i], alo[i]);
    }
#pragma unroll
    for (int i = 0; i < 2; ++i)
#pragma unroll
      for (int j = 0; j < 4; ++j) {
        acc[i][j] = __builtin_amdgcn_mfma_f32_16x16x32_bf16(ahi[i], bhi[j], acc[i][j], 0, 0, 0);
        acc[i][j] = __builtin_amdgcn_mfma_f32_16x16x32_bf16(ahi[i], blo[j], acc[i][j], 0, 0, 0);
        acc[i][j] = __builtin_amdgcn_mfma_f32_16x16x32_bf16(alo[i], bhi[j], acc[i][j], 0, 0, 0);
      }
  }

  __syncthreads();   // all waves' input loads done -> in-place output safe

  float psum[4], psq[4];
#pragma unroll
  for (int j = 0; j < 4; ++j) { psum[j] = 0.f; psq[j] = 0.f; }

#pragma unroll
  for (int j = 0; j < 4; ++j) {
    const int col = wc + 16 * j + m;
    const float bcol = bias[col];
    float mu = 0.f, rs = 0.f, gg = 0.f, bb = 0.f;
    float mu2 = 0.f, rs2 = 0.f, gg2 = 0.f, bb2 = 0.f;
    if (EPI == 3) {
      mu = stats[col] * invR;
      rs = rsqrtf(stats[128 + col] * invR - mu * mu + 1e-5f);
      gg = bng[col]; bb = bnb[col];
      mu2 = stats2[col] * invR2;
      rs2 = rsqrtf(stats2[128 + col] * invR2 - mu2 * mu2 + 1e-5f);
      gg2 = bng2[col]; bb2 = bnb2[col];
    }
#pragma unroll
    for (int i = 0; i < 2; ++i) {
      const int rowb = row0 + wr + 16 * i + 4 * q;
#pragma unroll
      for (int r = 0; r < 4; ++r) {
        const int gr = rowb + r;
        float y = acc[i][j][r] + bcol;
        if (EPI == 1) y = fmaxf(y, 0.f);
        if (EPI == 4) y += a1[(size_t)gr * H + col];
        if (EPI == 3) {
          int nid = ids[gr];
          float vf = (nid >= 0) ? 1.f : 0.f;
          bool root = (gr % Ksub) == 0;
          float t2v = b2f(a1b[(size_t)gr * H + col]);
          float h1 = fmaf((t2v - mu) * rs, gg, bb);
          float addv;
          if (root) {
            float c3v = a2[(size_t)nid * H + col];
            addv = fmaf((c3v - mu2) * rs2, gg2, bb2);
          } else {
            addv = y + a3[(size_t)(gr / Ksub) * H + col];
          }
          y = vf * fmaxf(h1 + addv, 0.f);
        }
        Y[(size_t)gr * H + col] = y;
        if (EPI == 2) { psum[j] += y; psq[j] += y * y; }
      }
    }
  }

  if (EPI == 2) {
    const int slot = 4 * (wv >> 1) + q;
#pragma unroll
    for (int j = 0; j < 4; ++j) {
      const int col = wc + 16 * j + m;
      sred[0][slot][col] = psum[j];
      sred[1][slot][col] = psq[j];
    }
    __syncthreads();
    if (tid < 128) {
      float s = 0.f, q2 = 0.f;
#pragma unroll
      for (int t = 0; t < 8; ++t) { s += sred[0][t][tid]; q2 += sred[1][t][tid]; }
      float* stc = stats + (blockIdx.x & 7) * 256;
      atomicAdd(stc + tid, s);
      atomicAdd(stc + 128 + tid, q2);
    }
  }
}

// --------------------------------------------------------------------------- prep / misc
// fold 8 sharded copies -> 1: out[b*256+c] = sum_k in[b*2048 + k*256 + c]
__global__ void k_fold(const float* __restrict__ in, float* __restrict__ out) {
  int b = blockIdx.x, c = threadIdx.x;
  const float* p = in + (size_t)b * 2048;
  float s = 0.f;
#pragma unroll
  for (int k = 0; k < 8; ++k) s += p[k * 256 + c];
  out[b * 256 + c] = s;
}

__global__ void k_split(const float* __restrict__ src, ushort* __restrict__ hi,
                        ushort* __restrict__ lo, int n) {
  int i = (blockIdx.x * 256 + threadIdx.x) * 4;
  if (i >= n) return;
  float4 v = ld4(src + i);
  float vv[4] = {v.x, v.y, v.z, v.w};
#pragma unroll
  for (int j = 0; j < 4; ++j) {
    ushort hv = f2b(vv[j]);
    hi[i + j] = hv;
    lo[i + j] = f2b(vv[j] - b2f(hv));
  }
}

__global__ void k_init_h(float* __restrict__ h, const int* __restrict__ node_ids,
                         const int* __restrict__ atom_ids,
                         const float* __restrict__ atom_tab, const float* __restrict__ dist_tab,
                         const float* __restrict__ log_probs, const float* __restrict__ logp_W,
                         const float* __restrict__ logp_b)
{
  int idx = blockIdx.x * 256 + threadIdx.x;
  if (idx >= SK * 32) return;
  int r = idx >> 5, c4 = (idx & 31) * 4;
  int nid = node_ids[r];
  float valid = nid >= 0 ? 1.f : 0.f;
  int cl = nid >= 0 ? nid : 0;
  int aid = atom_ids[cl];
  int dd = r % Ksub;                         // chain structure: dist == pos in chain
  float lp = log_probs[r / Ksub];
  float4 at = ld4(atom_tab + aid * H + c4);
  float4 dt = ld4(dist_tab + dd * H + c4);
  float4 w  = ld4(logp_W + c4);
  float4 bbv = ld4(logp_b + c4);
  float4 o;
  o.x = (at.x + dt.x + fmaxf(fmaf(lp, w.x, bbv.x), 0.f)) * valid;
  o.y = (at.y + dt.y + fmaxf(fmaf(lp, w.y, bbv.y), 0.f)) * valid;
  o.z = (at.z + dt.z + fmaxf(fmaf(lp, w.z, bbv.z), 0.f)) * valid;
  o.w = (at.w + dt.w + fmaxf(fmaf(lp, w.w, bbv.w), 0.f)) * valid;
  st4(h + (size_t)r * H + c4, o);
}

__global__ void k_bond_all(const float* __restrict__ bt, const float* __restrict__ lw,
                           const float* __restrict__ lb, float* __restrict__ bp_all)
{
  int mb = blockIdx.x;          // 0..7: l = mb>>1, which = mb&1 (0->W0, 1->W5)
  int c = threadIdx.x;
  int l = mb >> 1, wsel = (mb & 1) ? 5 : 0;
  const float* W = lw + ((size_t)l * 8 + wsel) * H * H;
  const float* b = lb + ((size_t)l * 8 + wsel) * H;
  for (int j = 0; j < 8; ++j) {
    float s = b[c];
    for (int k = 0; k < H; ++k) s = fmaf(bt[j * H + k], W[c * H + k], s);
    bp_all[(size_t)(mb * 8 + j) * H + c] = s;
  }
}

// c1[n] = mean of the 4 root rows; also zeroes c2f
__global__ void k_c1(const float* __restrict__ h, float* __restrict__ c1,
                     float* __restrict__ c2f) {
  int idx = blockIdx.x * 256 + threadIdx.x;
  if (idx >= NTOT * 32) return;
  int n = idx >> 5, c4 = (idx & 31) * 4;
  float o0 = 0.f, o1 = 0.f, o2 = 0.f, o3 = 0.f;
#pragma unroll
  for (int mi = 0; mi < 4; ++mi) {
    const float* p = h + ((size_t)(4 * n + mi) * Ksub) * H + c4;
    o0 += p[0]; o1 += p[1]; o2 += p[2]; o3 += p[3];
  }
  st4(c1 + (size_t)n * H + c4, make_float4(o0 * .25f, o1 * .25f, o2 * .25f, o3 * .25f));
  st4(c2f + (size_t)n * H + c4, make_float4(0.f, 0.f, 0.f, 0.f));
}

__global__ void k_agg(const float* __restrict__ x, const int* __restrict__ src,
                      const int* __restrict__ dst, const int* __restrict__ bid,
                      const float* __restrict__ bp, float* __restrict__ out, int E)
{
  int idx = blockIdx.x * 256 + threadIdx.x;
  if (idx >= E * 32) return;
  int e = idx >> 5, c4 = (idx & 31) * 4;
  int sv = src[e], dv = dst[e], bb = bid[e];
  float4 xv = ld4(x + (size_t)sv * H + c4);
  float4 bv = ld4(bp + (size_t)bb * H + c4);
  float* o = out + (size_t)dv * H + c4;
  atomicAdd(o + 0, fmaxf(xv.x + bv.x, 0.f));
  atomicAdd(o + 1, fmaxf(xv.y + bv.y, 0.f));
  atomicAdd(o + 2, fmaxf(xv.z + bv.z, 0.f));
  atomicAdd(o + 3, fmaxf(xv.w + bv.w, 0.f));
}

__global__ void k_pool(const float* __restrict__ h, float* __restrict__ hsub) {
  int idx = blockIdx.x * 256 + threadIdx.x;
  if (idx >= S * 32) return;
  int s = idx >> 5, c4 = (idx & 31) * 4;
  float a0 = 0.f, a1 = 0.f, a2 = 0.f, a3 = 0.f;
  const float* p = h + ((size_t)s * Ksub) * H + c4;
#pragma unroll
  for (int j = 0; j < Ksub; ++j) {
    a0 += p[0]; a1 += p[1]; a2 += p[2]; a3 += p[3];
    p += H;
  }
  st4(hsub + (size_t)s * H + c4, make_float4(a0, a1, a2, a3));
}

__global__ __launch_bounds__(128) void k_attn(const float* __restrict__ qb,
                                              const float* __restrict__ kb,
                                              const float* __restrict__ vb,
                                              float* __restrict__ ob)
{
  int n = blockIdx.x;
  int c = threadIdx.x;          // c = head*32 + d
  float q[4], kv[4], vv[4];
#pragma unroll
  for (int mi = 0; mi < 4; ++mi) {
    q[mi]  = qb[(size_t)(n * 4 + mi) * H + c];
    kv[mi] = kb[(size_t)(n * 4 + mi) * H + c];
    vv[mi] = vb[(size_t)(n * 4 + mi) * H + c];
  }
  const float scale = 0.17677669529663687f;   // 1/sqrt(32)
  float sc[4][4];
#pragma unroll
  for (int m1 = 0; m1 < 4; ++m1)
#pragma unroll
    for (int m2 = 0; m2 < 4; ++m2) {
      float p = q[m1] * kv[m2];
#pragma unroll
      for (int off = 16; off > 0; off >>= 1) p += __shfl_xor(p, off, 32);
      sc[m1][m2] = p * scale;
    }
#pragma unroll
  for (int m1 = 0; m1 < 4; ++m1) {
    float mx = fmaxf(fmaxf(sc[m1][0], sc[m1][1]), fmaxf(sc[m1][2], sc[m1][3]));
    float e0 = expf(sc[m1][0] - mx), e1 = expf(sc[m1][1] - mx);
    float e2 = expf(sc[m1][2] - mx), e3 = expf(sc[m1][3] - mx);
    float inv = 1.f / (e0 + e1 + e2 + e3);
    ob[(size_t)(n * 4 + m1) * H + c] =
        (e0 * vv[0] + e1 * vv[1] + e2 * vv[2] + e3 * vv[3]) * inv;
  }
}

__global__ void k_mean(const float* __restrict__ ha, float* __restrict__ ne) {
  int idx = blockIdx.x * 256 + threadIdx.x;
  if (idx >= NTOT * 32) return;
  int n = idx >> 5, c4 = (idx & 31) * 4;
  float4 a = ld4(ha + (size_t)(n * 4 + 0) * H + c4);
  float4 b = ld4(ha + (size_t)(n * 4 + 1) * H + c4);
  float4 c = ld4(ha + (size_t)(n * 4 + 2) * H + c4);
  float4 d = ld4(ha + (size_t)(n * 4 + 3) * H + c4);
  st4(ne + (size_t)n * H + c4,
      make_float4((a.x + b.x + c.x + d.x) * .25f, (a.y + b.y + c.y + d.y) * .25f,
                  (a.z + b.z + c.z + d.z) * .25f, (a.w + b.w + c.w + d.w) * .25f));
}

__global__ __launch_bounds__(256) void k_bn_stats(const float* __restrict__ X, int R,
                                                  float* __restrict__ stats) {
  __shared__ float sh[2][256];
  int c = threadIdx.x & 127;
  int rr = threadIdx.x >> 7;
  float s = 0.f, s2 = 0.f;
  for (int r = blockIdx.x * 2 + rr; r < R; r += gridDim.x * 2) {
    float v = X[(size_t)r * H + c];
    s += v; s2 += v * v;
  }
  sh[0][threadIdx.x] = s; sh[1][threadIdx.x] = s2;
  __syncthreads();
  if (rr == 0) {
    float* stc = stats + (blockIdx.x & 7) * 256;
    atomicAdd(stc + c,       s  + sh[0][threadIdx.x + 128]);
    atomicAdd(stc + 128 + c, s2 + sh[1][threadIdx.x + 128]);
  }
}

__global__ __launch_bounds__(128) void k_finalsum(const float* __restrict__ ne,
                                                  const float* __restrict__ stats,
                                                  const float* __restrict__ g,
                                                  const float* __restrict__ b,
                                                  float* __restrict__ out)
{
  int bg = blockIdx.x;           // graph id 0..63
  int c = threadIdx.x;
  const float invR = 1.0f / (float)NTOT;
  float mu = stats[c] * invR;
  float rs = rsqrtf(stats[128 + c] * invR - mu * mu + 1e-5f);
  float gg = g[c], bb = b[c];
  float acc = 0.f;
  for (int r = 0; r < 64; ++r) {
    float v = ne[(size_t)(bg * 64 + r) * H + c];
    acc += (v - mu) * rs * gg + bb;
  }
  out[(size_t)bg * H + c] = acc;
}

// ---------------------------------------------------------------------------
extern "C" void kernel_launch(void* const* d_in, const int* in_sizes, int n_in,
                              void* d_out, int out_size, void* d_ws, size_t ws_size,
                              hipStream_t stream)
{
  const int*   atom_ids   = (const int*)d_in[0];
  const int*   node_ids   = (const int*)d_in[1];
  const int*   intra_bid  = (const int*)d_in[3];
  const int*   edge_index = (const int*)d_in[4];
  const int*   canon_bid  = (const int*)d_in[5];
  const float* log_probs  = (const float*)d_in[7];
  const float* atom_tab   = (const float*)d_in[8];
  const float* bond_tab   = (const float*)d_in[9];
  const float* dist_tab   = (const float*)d_in[10];
  const float* logp_W     = (const float*)d_in[11];
  const float* logp_b     = (const float*)d_in[12];
  const float* lw         = (const float*)d_in[13];
  const float* lb         = (const float*)d_in[14];
  const float* bn_g       = (const float*)d_in[15];
  const float* bn_b       = (const float*)d_in[16];
  const float* eps        = (const float*)d_in[17];
  const float* mha_in_W   = (const float*)d_in[18];
  const float* mha_in_b   = (const float*)d_in[19];
  const float* mha_out_W  = (const float*)d_in[20];
  const float* mha_out_b  = (const float*)d_in[21];
  const float* ro_g       = (const float*)d_in[22];
  const float* ro_b       = (const float*)d_in[23];

  const int E2 = in_sizes[4] / 2;    // 32768 canonical edges
  const int* src2 = edge_index, *dst2 = edge_index + E2;

  // ---- workspace layout ----
  const size_t SKH = (size_t)SK * H;
  const size_t SH  = (size_t)S * H;
  char* wsb = (char*)d_ws;
  float*  h      = (float*)wsb;     wsb += SKH * 4;                 // [SK,H] fp32
  ushort* tb     = (ushort*)wsb;    wsb += SKH * 2;                 // [SK,H] bf16 (t2)
  float*  rproj  = (float*)wsb;     wsb += SH * 4;
  float*  c1     = (float*)wsb;     wsb += (size_t)NTOT * H * 4;
  float*  c2b    = (float*)wsb;     wsb += (size_t)NTOT * H * 4;
  float*  c3     = (float*)wsb;     wsb += (size_t)NTOT * H * 4;
  float*  c2f    = (float*)wsb;     wsb += (size_t)NTOT * H * 4;
  float*  bp_all = (float*)wsb;     wsb += (size_t)64 * H * 4;
  float*  statsA = (float*)wsb;     wsb += 9 * 2048 * 4;            // sharded
  float*  statsF = (float*)wsb;     wsb += 9 * 256 * 4;             // folded
  ushort* lwhi   = (ushort*)wsb;    wsb += (size_t)4 * 8 * H * H * 2;
  ushort* lwlo   = (ushort*)wsb;    wsb += (size_t)4 * 8 * H * H * 2;
  ushort* mihi   = (ushort*)wsb;    wsb += (size_t)3 * H * H * 2;
  ushort* milo   = (ushort*)wsb;    wsb += (size_t)3 * H * H * 2;
  ushort* mohi   = (ushort*)wsb;    wsb += (size_t)H * H * 2;
  ushort* molo   = (ushort*)wsb;    wsb += (size_t)H * H * 2;
  float*  hsub   = (float*)wsb;     wsb += SH * 4;
  float*  qkv    = (float*)wsb;     wsb += 3 * SH * 4;
  float*  ob     = (float*)wsb;     wsb += SH * 4;
  float*  ne     = (float*)wsb;     wsb += (size_t)NTOT * H * 4;
  float*  out    = (float*)d_out;

  hipMemsetAsync(statsA, 0, 9 * 2048 * sizeof(float), stream);
  const int NLW = 4 * 8 * H * H, NMI = 3 * H * H, NMO = H * H;
  k_split<<<(NLW / 4 + 255) / 256, 256, 0, stream>>>(lw, lwhi, lwlo, NLW);
  k_split<<<(NMI / 4 + 255) / 256, 256, 0, stream>>>(mha_in_W, mihi, milo, NMI);
  k_split<<<(NMO / 4 + 255) / 256, 256, 0, stream>>>(mha_out_W, mohi, molo, NMO);
  k_bond_all<<<8, 128, 0, stream>>>(bond_tab, lw, lb, bp_all);
  k_init_h<<<(SK * 32 + 255) / 256, 256, 0, stream>>>(h, node_ids, atom_ids,
      atom_tab, dist_tab, log_probs, logp_W, logp_b);

  for (int l = 0; l < 4; ++l) {
    const ushort* Whi = lwhi + (size_t)l * 8 * H * H;
    const ushort* Wlo = lwlo + (size_t)l * 8 * H * H;
    const float* bb = lb + (size_t)l * 8 * H;
    const float* g0 = bn_g + (l * 2 + 0) * H, *b0  = bn_b + (l * 2 + 0) * H;
    const float* g1 = bn_g + (l * 2 + 1) * H, *b1v = bn_b + (l * 2 + 1) * H;
    const float* eps0 = eps + l * 2, *eps1 = eps + l * 2 + 1;
    float* st0raw = statsA + (size_t)(2 * l + 0) * 2048;
    float* st1raw = statsA + (size_t)(2 * l + 1) * 2048;
    float* st0 = statsF + (size_t)l * 512;
    float* st1 = statsF + (size_t)l * 512 + 256;
    const float* bp0 = bp_all + (size_t)(l * 2 + 0) * 8 * H;
    const float* bp1 = bp_all + (size_t)(l * 2 + 1) * 8 * H;

    // fused: tb = bf16( (chain-GINE(h) @ W1 -> relu) @ W2 + b2 ), + BN0 stats
    mm12<<<SK / 64, 256, 0, stream>>>(h, Whi + 1 * H * H, Wlo + 1 * H * H, bb + 1 * H,
        Whi + 2 * H * H, Wlo + 2 * H * H, bb + 2 * H, tb, bp0, intra_bid, eps0, st0raw);
    // rproj[s] = h[root(s)] @ W4^T + b4  (independent; fills bubbles)
    mmN<2, 0><<<dim3(S / 64, 1), 256, 0, stream>>>(h, Whi + 4 * H * H, Wlo + 4 * H * H,
        bb + 4 * H, rproj, nullptr, nullptr, nullptr, nullptr, nullptr, nullptr,
        nullptr, nullptr, nullptr, nullptr, nullptr, nullptr, 0.f, 0.f, 0);
    // canonical path
    k_c1<<<(NTOT * 32 + 255) / 256, 256, 0, stream>>>(h, c1, c2f);
    k_agg<<<(E2 * 32 + 255) / 256, 256, 0, stream>>>(c1, src2, dst2, canon_bid, bp1, c2f, E2);
    mmN<1, 1><<<dim3(NTOT / 64, 1), 256, 0, stream>>>(c1, Whi + 6 * H * H, Wlo + 6 * H * H,
        bb + 6 * H, c2b, c2f, nullptr, nullptr, nullptr, nullptr, nullptr, nullptr,
        nullptr, nullptr, nullptr, nullptr, eps1, 0.f, 0.f, 0);
    mmN<0, 2><<<dim3(NTOT / 64, 1), 256, 0, stream>>>(c2b, Whi + 7 * H * H, Wlo + 7 * H * H,
        bb + 7 * H, c3, nullptr, nullptr, nullptr, nullptr, nullptr, st1raw, nullptr,
        nullptr, nullptr, nullptr, nullptr, nullptr, 0.f, 0.f, 0);
    // fold sharded stats (st0 from mm12, st1 from canonical GEMM2)
    k_fold<<<2, 256, 0, stream>>>(st0raw, st0);
    // combine: h = relu( BN0(tb) + (root ? BN1(c3raw[nid]) : h@W3+b3 + rproj[s]) ) * valid
    mmN<0, 3><<<dim3(SK / 64, 1), 256, 0, stream>>>(h, Whi + 3 * H * H, Wlo + 3 * H * H,
        bb + 3 * H, h, nullptr, tb, c3, rproj, node_ids, st0, g0, b0, st1, g1, b1v,
        nullptr, 1.0f / (float)SK, 1.0f / (float)NTOT, 0);
  }

  // ---- pooling + MHA + readout ----
  k_pool<<<(S * 32 + 255) / 256, 256, 0, stream>>>(h, hsub);
  mmN<0, 0><<<dim3(S / 64, 3), 256, 0, stream>>>(hsub, mihi, milo, mha_in_b, qkv,
      nullptr, nullptr, nullptr, nullptr, nullptr, nullptr, nullptr, nullptr, nullptr,
      nullptr, nullptr, nullptr, 0.f, 0.f, SH);
  k_attn<<<NTOT, 128, 0, stream>>>(qkv, qkv + SH, qkv + 2 * SH, ob);
  mmN<0, 4><<<dim3(S / 64, 1), 256, 0, stream>>>(ob, mohi, molo, mha_out_b, ob,
      hsub, nullptr, nullptr, nullptr, nullptr, nullptr, nullptr, nullptr, nullptr,
      nullptr, nullptr, nullptr, 0.f, 0.f, 0);
  k_mean<<<(NTOT * 32 + 255) / 256, 256, 0, stream>>>(ob, ne);
  float* stFraw = statsA + (size_t)8 * 2048;
  float* stF    = statsF + (size_t)4 * 512;
  k_bn_stats<<<512, 256, 0, stream>>>(ne, NTOT, stFraw);
  k_fold<<<1, 256, 0, stream>>>(stFraw, stF);
  k_finalsum<<<64, 128, 0, stream>>>(ne, stF, ro_g, ro_b, out);
}